// Round 1
// 268.246 us; speedup vs baseline: 1.0642x; 1.0642x over previous
//
#include <hip/hip_runtime.h>
#include <math.h>

typedef __attribute__((ext_vector_type(8))) short short8;
typedef __attribute__((ext_vector_type(4))) float f32x4;
typedef __attribute__((ext_vector_type(4))) unsigned int uint4v;

#define HIDDEN 1024
#define QOUT 2048
#define KVOUT 1024
#define HD 128
#define TSEQ 2048

__device__ __forceinline__ float bf2f(unsigned short h) {
    union { unsigned int u; float f; } x; x.u = ((unsigned int)h) << 16; return x.f;
}
__device__ __forceinline__ unsigned short f2bf(float f) {
    union { float f; unsigned int u; } x; x.f = f;
    unsigned int r = (x.u + 0x7fffu + ((x.u >> 16) & 1u)) >> 16;
    return (unsigned short)r;
}
// HW packed f32->bf16 (RNE, same semantics as f2bf pair) -- 1 VALU op per 2 values
__device__ __forceinline__ unsigned int cvtpk(float lo, float hi) {
    unsigned int r;
    asm("v_cvt_pk_bf16_f32 %0, %1, %2" : "=v"(r) : "v"(lo), "v"(hi));
    return r;
}

// async global->LDS, 16B per lane; dest = wave-uniform base + lane*16
__device__ __forceinline__ void glds16(const unsigned short* g, unsigned short* l) {
    __builtin_amdgcn_global_load_lds(
        (const __attribute__((address_space(1))) unsigned int*)g,
        (__attribute__((address_space(3))) unsigned int*)l, 16, 0, 0);
}

// ---------------- prep: cast x->bf16  +  4 weight transposes (fp32 KxN -> bf16 NxK) ---------
__global__ __launch_bounds__(256) void prep(const float* __restrict__ x,
                                            const float* __restrict__ Wq,
                                            const float* __restrict__ Wk,
                                            const float* __restrict__ Wv,
                                            const float* __restrict__ Wo,
                                            unsigned short* __restrict__ xb,
                                            unsigned short* __restrict__ Wt,
                                            unsigned short* __restrict__ Wot) {
    int bid = blockIdx.x;
    int tid = threadIdx.x;
    if (bid < 4096) {  // cast: 1M float4
        int i = bid * 256 + tid;
        float4 v = *(const float4*)(x + (size_t)i * 4);
        unsigned short o[4] = {f2bf(v.x), f2bf(v.y), f2bf(v.z), f2bf(v.w)};
        *(unsigned long long*)(xb + (size_t)i * 4) = *(unsigned long long*)o;
        return;
    }
    bid -= 4096;
    const float* W; unsigned short* D; int K, N;
    if (bid < 512)       { W = Wq; D = Wt;                          K = 1024; N = 2048; }
    else if (bid < 768)  { bid -= 512;  W = Wk; D = Wt + (size_t)2048 * 1024; K = 1024; N = 1024; }
    else if (bid < 1024) { bid -= 768;  W = Wv; D = Wt + (size_t)3072 * 1024; K = 1024; N = 1024; }
    else                 { bid -= 1024; W = Wo; D = Wot;                      K = 2048; N = 1024; }
    __shared__ __attribute__((aligned(16))) unsigned short Ls[64 * 72];
    int ntiles = N >> 6;
    int kt = bid / ntiles, nt = bid - kt * ntiles;
    int k0 = kt * 64, n0 = nt * 64;
    for (int t = 0; t < 4; t++) {
        int idx = tid + t * 256;
        int r = idx >> 4, seg = idx & 15;
        float4 v = *(const float4*)(W + (size_t)(k0 + r) * N + n0 + seg * 4);
        int c = seg * 4;
        Ls[(c + 0) * 72 + r] = f2bf(v.x);
        Ls[(c + 1) * 72 + r] = f2bf(v.y);
        Ls[(c + 2) * 72 + r] = f2bf(v.z);
        Ls[(c + 3) * 72 + r] = f2bf(v.w);
    }
    __syncthreads();
    for (int t = 0; t < 2; t++) {
        int idx = tid + t * 256;
        int rr = idx >> 3, seg = idx & 7;
        uint4v v = *(const uint4v*)(Ls + rr * 72 + seg * 8);
        *(uint4v*)(D + (size_t)(n0 + rr) * K + k0 + seg * 8) = v;
    }
}

// ---------------- GEMM: C[M,N] = A[M,K](bf16) @ Bt[N,K]^T(bf16) ----------------
// Single-barrier double-buffered glds16 staging: prefetch(it+1) issued AFTER the
// barrier, so the next barrier's vmcnt(0) drain overlaps with this iteration's MFMA.
template <int OUT_BF16, int BN>
__global__ __launch_bounds__(256) void gemm_bt(const unsigned short* __restrict__ A,
                                               const unsigned short* __restrict__ Bt,
                                               void* __restrict__ Cout,
                                               int M, int N, int K) {
    constexpr int MT = (BN == 128) ? 4 : 2;
    __shared__ __attribute__((aligned(16))) unsigned short As[2][128 * 32];
    __shared__ __attribute__((aligned(16))) unsigned short Bs[2][BN * 32];
    const int tid = threadIdx.x;
    const int lane = tid & 63;
    const int warp = tid >> 6;
    const int ln = lane & 15;
    const int quad = lane >> 4;
    const int wm = (BN == 128) ? (warp >> 1) : warp;
    const int wn = (BN == 128) ? (warp & 1) : 0;
    const int m0 = blockIdx.y * 128;
    const int n0 = blockIdx.x * BN;

    const int srow = lane >> 2;
    const int schunk = (lane & 3) ^ (srow & 3);
    const unsigned short* Ag = A + (size_t)(m0 + warp * 16 + srow) * K + schunk * 8;
    const unsigned short* Bg = Bt + (size_t)(n0 + warp * 16 + srow) * K + schunk * 8;

    f32x4 acc[MT][4];
#pragma unroll
    for (int i = 0; i < MT; i++)
#pragma unroll
        for (int j = 0; j < 4; j++) acc[i][j] = (f32x4){0.f, 0.f, 0.f, 0.f};

    auto stage = [&](int k0, int bi) {
        glds16(Ag + k0, As[bi] + warp * 16 * 32);
        glds16(Ag + (size_t)64 * K + k0, As[bi] + warp * 16 * 32 + 64 * 32);
        glds16(Bg + k0, Bs[bi] + warp * 16 * 32);
        if (BN == 128) glds16(Bg + (size_t)64 * K + k0, Bs[bi] + warp * 16 * 32 + 64 * 32);
    };

    const int rq = quad ^ (ln & 3);   // swizzled read chunk
    const int KI = K >> 5;
    stage(0, 0);
    for (int it = 0; it < KI; it++) {
        __syncthreads();            // drains my glds for buf it&1
        if (it + 1 < KI) stage((it + 1) << 5, (it + 1) & 1);
        const unsigned short* Ab = As[it & 1];
        const unsigned short* Bb = Bs[it & 1];
        short8 af[MT], bf[4];
#pragma unroll
        for (int mt = 0; mt < MT; mt++)
            af[mt] = *(const short8*)(Ab + (wm * (MT * 16) + mt * 16 + ln) * 32 + rq * 8);
#pragma unroll
        for (int nt = 0; nt < 4; nt++)
            bf[nt] = *(const short8*)(Bb + (wn * 64 + nt * 16 + ln) * 32 + rq * 8);
#pragma unroll
        for (int mt = 0; mt < MT; mt++)
#pragma unroll
            for (int nt = 0; nt < 4; nt++)
                acc[mt][nt] = __builtin_amdgcn_mfma_f32_16x16x32_bf16(bf[nt], af[mt], acc[mt][nt], 0, 0, 0);
    }
#pragma unroll
    for (int mt = 0; mt < MT; mt++) {
        int row = m0 + wm * (MT * 16) + mt * 16 + ln;
#pragma unroll
        for (int nt = 0; nt < 4; nt++) {
            int colb = n0 + wn * 64 + nt * 16 + quad * 4;
            if (OUT_BF16) {
                unsigned long long pk =
                    (unsigned long long)cvtpk(acc[mt][nt][0], acc[mt][nt][1]) |
                    ((unsigned long long)cvtpk(acc[mt][nt][2], acc[mt][nt][3]) << 32);
                *(unsigned long long*)((unsigned short*)Cout + (size_t)row * N + colb) = pk;
            } else {
                *(f32x4*)((float*)Cout + (size_t)row * N + colb) = acc[mt][nt];
            }
        }
    }
}

// ---------------- fused norm_rope (blocks < 24576) + v_transpose (rest) ----------------
// Q additionally pre-scaled by (1/sqrt(128))*log2(e) so attn's QK^T lands directly in
// the exp2 domain (saves 16 v_mul per strip-iter on the attn critical path; same single
// bf16 rounding as before).
__global__ __launch_bounds__(256) void nrvt(const unsigned short* __restrict__ QKV,
                                            const float* __restrict__ qw,
                                            const float* __restrict__ kw,
                                            unsigned short* __restrict__ Q,
                                            unsigned short* __restrict__ Kb,
                                            unsigned short* __restrict__ Vt) {
    if (blockIdx.x < 24576) {
        int warp = threadIdx.x >> 6;
        int lane = threadIdx.x & 63;
        int gid = blockIdx.x * 4 + warp;
        int tok = gid / 24;
        int slot = gid - tok * 24;
        int b = tok >> 11, t = tok & 2047;
        const float* w;
        unsigned short* dst;
        int col0;
        float sc;
        if (slot < 16) {
            col0 = slot * HD;
            dst = Q + ((size_t)(b * 16 + slot) * TSEQ + t) * HD;
            w = qw;
            sc = 0.12750580997495268f;  // (1/sqrt(128)) * log2(e) folded into Q
        } else {
            int hk = slot - 16;
            col0 = QOUT + hk * HD;
            dst = Kb + ((size_t)(b * 8 + hk) * TSEQ + t) * HD;
            w = kw;
            sc = 1.0f;
        }
        const unsigned short* row = QKV + (size_t)tok * 4096 + col0;
        float e0 = bf2f(row[lane]), e1 = bf2f(row[lane + 64]);
        float ss = e0 * e0 + e1 * e1;
        for (int off = 1; off < 64; off <<= 1) ss += __shfl_xor(ss, off);
        float rr = rsqrtf(ss * (1.0f / 128.0f) + 1e-6f);
        float n0 = e0 * rr * w[lane];
        float n1 = e1 * rr * w[lane + 64];
        float invf = __builtin_exp2f(-(float)lane * 0.20762050593045951f);
        float ang = (float)t * invf;
        float sf, cf;
        __sincosf(ang, &sf, &cf);
        dst[lane] = f2bf((n0 * cf - n1 * sf) * sc);
        dst[lane + 64] = f2bf((n1 * cf + n0 * sf) * sc);
        return;
    }
    // v_transpose
    __shared__ __attribute__((aligned(16))) unsigned short Ls[128 * 72];
    int bid = blockIdx.x - 24576;
    int tt = bid & 31, hk = (bid >> 5) & 7, b = bid >> 8;
    int t0 = tt * 64;
    int tid = threadIdx.x;
    const unsigned short* base = QKV + (size_t)(b * 2048 + t0) * 4096 + 3072 + hk * 128;
    for (int i = 0; i < 4; i++) {
        int idx = tid + i * 256;
        int r = idx >> 4, seg = idx & 15;
        uint4v v = *(const uint4v*)(base + (size_t)r * 4096 + seg * 8);
        unsigned short* pv = (unsigned short*)&v;
        int d = seg * 8;
        for (int jj = 0; jj < 8; jj++) Ls[(d + jj) * 72 + r] = pv[jj];
    }
    __syncthreads();
    unsigned short* out = Vt + (size_t)(b * 8 + hk) * 128 * 2048;
    for (int i = 0; i < 4; i++) {
        int idx = tid + i * 256;
        int d = idx >> 3, seg = idx & 7;
        uint4v v = *(const uint4v*)(Ls + d * 72 + seg * 8);
        *(uint4v*)(out + (size_t)d * 2048 + t0 + seg * 8) = v;
    }
}

// ---------------- flash attention v8: defer-max + mfma row-sum + cvt_pk + setprio ----------
// grid (16 p, 32 b*h), 256 thr. Wave owns 16 rows of tile p (strip 0, active j<=p)
// and 16 rows of tile 31-p (strip 1, always active). Prefetch j+1 after the barrier.
// Softmax critical path: lane-local max check (no shuffles common-path, T13 THR=8),
// row-sum l accumulated by 2 extra MFMAs against a ones-fragment (MFMA pipe at ~15%,
// this is free and uses the *same* bf16 P as PV), P packed with v_cvt_pk_bf16_f32.
__global__ __launch_bounds__(256, 2) void attn(const unsigned short* __restrict__ Q,
                                               const unsigned short* __restrict__ Kg,
                                               const unsigned short* __restrict__ Vt,
                                               unsigned short* __restrict__ Og) {
    __shared__ __attribute__((aligned(16))) unsigned short Ks[2][64 * 128];  // swizzled (kv, d)
    __shared__ __attribute__((aligned(16))) unsigned short Vs[2][128 * 64];  // swizzled (d, kv)
    __shared__ __attribute__((aligned(16))) unsigned short Ps[4][16 * 72];
    const int p = blockIdx.x;
    const int bh = blockIdx.y;
    const int b = bh >> 4, h = bh & 15, hk = h >> 1;
    const int tid = threadIdx.x;
    const int warp = tid >> 6, lane = tid & 63, ln = lane & 15, quad = lane >> 4;
    const int strip[2] = { p * 64 + warp * 16, (31 - p) * 64 + warp * 16 };
    const int jdiag[2] = { p, 31 - p };

    const unsigned short* Kbase = Kg + (size_t)(b * 8 + hk) * TSEQ * HD;
    const unsigned short* Vbase = Vt + (size_t)(b * 8 + hk) * HD * TSEQ;
    const unsigned short* Qh = Q + (size_t)(b * 16 + h) * TSEQ * HD;

    short8 qf[2][4];
#pragma unroll
    for (int st = 0; st < 2; st++)
#pragma unroll
        for (int kt = 0; kt < 4; kt++)
            qf[st][kt] = *(const short8*)(Qh + (size_t)(strip[st] + ln) * HD + kt * 32 + quad * 8);

    f32x4 o[2][8];
    f32x4 lac[2];
#pragma unroll
    for (int st = 0; st < 2; st++) {
        lac[st] = (f32x4){0.f, 0.f, 0.f, 0.f};
#pragma unroll
        for (int ot = 0; ot < 8; ot++) o[st][ot] = (f32x4){0.f, 0.f, 0.f, 0.f};
    }
    float m_[2] = {-1e30f, -1e30f};

    const int kr = lane >> 4;
    const int kc = lane & 15;
    const int vr = lane >> 3;
    const int vc = lane & 7;

    auto stage_kv = [&](int jt, int bi) {
        const int j0s = jt * 64;
        unsigned short* KsB = Ks[bi];
        unsigned short* VsB = Vs[bi];
#pragma unroll
        for (int c = 0; c < 4; c++) {   // K: LDS[r][c] = K[r][c ^ (r&15)]
            int row = warp * 16 + c * 4 + kr;
            glds16(Kbase + (size_t)(j0s + row) * HD + ((kc ^ (row & 15)) * 8),
                   KsB + (warp * 16 + c * 4) * 128);
        }
#pragma unroll
        for (int c = 0; c < 4; c++) {   // V^T: LDS[d][c] = V[d][c ^ (d&7)]
            int d = warp * 32 + c * 8 + vr;
            glds16(Vbase + (size_t)d * TSEQ + j0s + ((vc ^ (d & 7)) * 8),
                   VsB + (warp * 32 + c * 8) * 64);
        }
    };

    // bf16 1.0 fragment for row-sum MFMA (B = all-ones 16x32)
    short8 ones8;
#pragma unroll
    for (int i = 0; i < 8; i++) ones8[i] = (short)0x3F80;

    const int nT = 32 - p;
    stage_kv(0, 0);
    for (int j = 0; j < nT; j++) {
        __syncthreads();                 // drains my glds for buf j&1 (prev iter's prefetch)
        if (j + 1 < nT) stage_kv(j + 1, (j + 1) & 1);
        const unsigned short* KsC = Ks[j & 1];
        const unsigned short* VsC = Vs[j & 1];
        const bool act0 = (j <= jdiag[0]);
        // ---- QK^T for both strips, kf shared (Q pre-scaled: s is in exp2 domain) ----
        f32x4 s[2][4];
#pragma unroll
        for (int kb = 0; kb < 4; kb++) {
            s[0][kb] = (f32x4){0.f, 0.f, 0.f, 0.f};
            s[1][kb] = (f32x4){0.f, 0.f, 0.f, 0.f};
        }
        __builtin_amdgcn_s_setprio(1);
#pragma unroll
        for (int kt = 0; kt < 4; kt++) {
            short8 kf[4];
#pragma unroll
            for (int kb = 0; kb < 4; kb++)
                kf[kb] = *(const short8*)(KsC + (kb * 16 + ln) * 128 + (((kt * 4 + quad) ^ ln) * 8));
#pragma unroll
            for (int kb = 0; kb < 4; kb++)
                s[1][kb] = __builtin_amdgcn_mfma_f32_16x16x32_bf16(kf[kb], qf[1][kt], s[1][kb], 0, 0, 0);
            if (act0)
#pragma unroll
                for (int kb = 0; kb < 4; kb++)
                    s[0][kb] = __builtin_amdgcn_mfma_f32_16x16x32_bf16(kf[kb], qf[0][kt], s[0][kb], 0, 0, 0);
        }
        __builtin_amdgcn_s_setprio(0);
        // ---- softmax + P staging per strip: defer-max (THR=8), shuffle-free common path ----
        short8 pf[2][2];
        bool needR[2] = {false, false};
        float alpha[2] = {1.f, 1.f};
#pragma unroll
        for (int st = 0; st < 2; st++) {
            if (st == 0 && !act0) continue;
            float mk[4];
            if (j == jdiag[st]) {
                const int qloc = warp * 16 + ln;
#pragma unroll
                for (int kb = 0; kb < 4; kb++) {
#pragma unroll
                    for (int r = 0; r < 4; r++) {
                        int kvloc = kb * 16 + quad * 4 + r;
                        if (kvloc > qloc) s[st][kb][r] = -1e30f;
                    }
                    mk[kb] = fmaxf(fmaxf(s[st][kb][0], s[st][kb][1]),
                                   fmaxf(s[st][kb][2], s[st][kb][3]));
                }
            } else {
#pragma unroll
                for (int kb = 0; kb < 4; kb++)
                    mk[kb] = fmaxf(fmaxf(s[st][kb][0], s[st][kb][1]),
                                   fmaxf(s[st][kb][2], s[st][kb][3]));
            }
            float mx = fmaxf(fmaxf(mk[0], mk[1]), fmaxf(mk[2], mk[3]));
            float mn = m_[st];
            // lane-local max is a lower bound on the row max; if every lane is within
            // THR=8 of m, the row max is too -> keep m (P bounded by 2^8, bf16-safe).
            if (!__all(mx <= mn + 8.0f)) {
                mx = fmaxf(mx, __shfl_xor(mx, 16));
                mx = fmaxf(mx, __shfl_xor(mx, 32));
                mn = fmaxf(m_[st], mx);
                alpha[st] = __builtin_exp2f(m_[st] - mn);
                m_[st] = mn;
                needR[st] = true;
            }
#pragma unroll
            for (int kb = 0; kb < 4; kb++) {
                float p0 = __builtin_exp2f(s[st][kb][0] - mn);
                float p1 = __builtin_exp2f(s[st][kb][1] - mn);
                float p2 = __builtin_exp2f(s[st][kb][2] - mn);
                float p3 = __builtin_exp2f(s[st][kb][3] - mn);
                unsigned long long pk =
                    (unsigned long long)cvtpk(p0, p1) |
                    ((unsigned long long)cvtpk(p2, p3) << 32);
                *(unsigned long long*)(&Ps[warp][ln * 72 + kb * 16 + quad * 4]) = pk;
            }
            pf[st][0] = *(const short8*)(&Ps[warp][ln * 72 + quad * 8]);
            pf[st][1] = *(const short8*)(&Ps[warp][ln * 72 + 32 + quad * 8]);
        }
        // ---- rescale O and l (uniform branch, rare after first tile) ----
        if (act0 && needR[0]) {
            float a = alpha[0];
#pragma unroll
            for (int ot = 0; ot < 8; ot++)
#pragma unroll
                for (int r = 0; r < 4; r++) o[0][ot][r] *= a;
#pragma unroll
            for (int r = 0; r < 4; r++) lac[0][r] *= a;
        }
        if (needR[1]) {
            float a = alpha[1];
#pragma unroll
            for (int ot = 0; ot < 8; ot++)
#pragma unroll
                for (int r = 0; r < 4; r++) o[1][ot][r] *= a;
#pragma unroll
            for (int r = 0; r < 4; r++) lac[1][r] *= a;
        }
        // ---- PV + row-sum, vf shared across strips; operand-swapped (O: col=q=ln, rows=d) ----
        __builtin_amdgcn_s_setprio(1);
        lac[1] = __builtin_amdgcn_mfma_f32_16x16x32_bf16(ones8, pf[1][0], lac[1], 0, 0, 0);
        lac[1] = __builtin_amdgcn_mfma_f32_16x16x32_bf16(ones8, pf[1][1], lac[1], 0, 0, 0);
        if (act0) {
            lac[0] = __builtin_amdgcn_mfma_f32_16x16x32_bf16(ones8, pf[0][0], lac[0], 0, 0, 0);
            lac[0] = __builtin_amdgcn_mfma_f32_16x16x32_bf16(ones8, pf[0][1], lac[0], 0, 0, 0);
        }
#pragma unroll
        for (int ot = 0; ot < 8; ot++) {
            short8 vf0 = *(const short8*)(VsC + (ot * 16 + ln) * 64 + ((quad ^ (ln & 7)) * 8));
            short8 vf1 = *(const short8*)(VsC + (ot * 16 + ln) * 64 + (((4 + quad) ^ (ln & 7)) * 8));
            o[1][ot] = __builtin_amdgcn_mfma_f32_16x16x32_bf16(vf0, pf[1][0], o[1][ot], 0, 0, 0);
            o[1][ot] = __builtin_amdgcn_mfma_f32_16x16x32_bf16(vf1, pf[1][1], o[1][ot], 0, 0, 0);
            if (act0) {
                o[0][ot] = __builtin_amdgcn_mfma_f32_16x16x32_bf16(vf0, pf[0][0], o[0][ot], 0, 0, 0);
                o[0][ot] = __builtin_amdgcn_mfma_f32_16x16x32_bf16(vf1, pf[0][1], o[0][ot], 0, 0, 0);
            }
        }
        __builtin_amdgcn_s_setprio(0);
    }
    // epilogue: lane has q = strip+ln; regs are 4 consecutive d -> 8B stores
#pragma unroll
    for (int st = 0; st < 2; st++) {
        float inv = 1.0f / lac[st][0];
        size_t rowoff = ((size_t)(b * TSEQ + strip[st] + ln)) * QOUT + h * 128 + quad * 4;
#pragma unroll
        for (int ot = 0; ot < 8; ot++) {
            unsigned long long pk =
                (unsigned long long)cvtpk(o[st][ot][0] * inv, o[st][ot][1] * inv) |
                ((unsigned long long)cvtpk(o[st][ot][2] * inv, o[st][ot][3] * inv) << 32);
            *(unsigned long long*)(Og + rowoff + ot * 16) = pk;
        }
    }
}

extern "C" void kernel_launch(void* const* d_in, const int* in_sizes, int n_in,
                              void* d_out, int out_size, void* d_ws, size_t ws_size,
                              hipStream_t stream) {
    (void)in_sizes; (void)n_in; (void)out_size;
    const float* x  = (const float*)d_in[0];
    const float* Wq = (const float*)d_in[1];
    const float* Wk = (const float*)d_in[2];
    const float* Wv = (const float*)d_in[3];
    const float* Wo = (const float*)d_in[4];
    const float* qw = (const float*)d_in[5];
    const float* kw = (const float*)d_in[6];

    char* ws = (char*)d_ws;
    const size_t MB = 1024 * 1024;
    unsigned short* Wt   = (unsigned short*)(ws);            // 8 MB
    unsigned short* Wot  = (unsigned short*)(ws + 8 * MB);   // 4 MB
    unsigned short* QKVb = (unsigned short*)(ws + 12 * MB);  // 32 MB (bf16)
    unsigned short* xb   = (unsigned short*)(ws + 44 * MB);  // 8 MB
    unsigned short* Qb   = (unsigned short*)(ws + 52 * MB);  // 16 MB
    unsigned short* Kb   = (unsigned short*)(ws + 68 * MB);  // 8 MB
    unsigned short* Vtb  = (unsigned short*)(ws + 76 * MB);  // 8 MB
    unsigned short* Ob   = (unsigned short*)(ws + 84 * MB);  // 16 MB
    if (ws_size < 100 * MB) return;

    prep<<<dim3(5632), 256, 0, stream>>>(x, Wq, Wk, Wv, Wo, xb, Wt, Wot);
    gemm_bt<1, 128><<<dim3(32, 32), 256, 0, stream>>>(xb, Wt, QKVb, 4096, 4096, 1024);
    nrvt<<<dim3(25088), 256, 0, stream>>>(QKVb, qw, kw, Qb, Kb, Vtb);
    attn<<<dim3(16, 32), 256, 0, stream>>>(Qb, Kb, Vtb, Ob);
    gemm_bt<0, 64><<<dim3(16, 32), 256, 0, stream>>>(Ob, Wot, (float*)d_out, 4096, 1024, 2048);
}

// Round 2
// 262.604 us; speedup vs baseline: 1.0870x; 1.0215x over previous
//
#include <hip/hip_runtime.h>
#include <math.h>

typedef __attribute__((ext_vector_type(8))) short short8;
typedef __attribute__((ext_vector_type(4))) float f32x4;
typedef __attribute__((ext_vector_type(4))) unsigned int uint4v;

#define HIDDEN 1024
#define QOUT 2048
#define KVOUT 1024
#define HD 128
#define TSEQ 2048

__device__ __forceinline__ float bf2f(unsigned short h) {
    union { unsigned int u; float f; } x; x.u = ((unsigned int)h) << 16; return x.f;
}
__device__ __forceinline__ unsigned short f2bf(float f) {
    union { float f; unsigned int u; } x; x.f = f;
    unsigned int r = (x.u + 0x7fffu + ((x.u >> 16) & 1u)) >> 16;
    return (unsigned short)r;
}
// HW packed f32->bf16 (RNE, same semantics as f2bf pair) -- 1 VALU op per 2 values
__device__ __forceinline__ unsigned int cvtpk(float lo, float hi) {
    unsigned int r;
    asm("v_cvt_pk_bf16_f32 %0, %1, %2" : "=v"(r) : "v"(lo), "v"(hi));
    return r;
}

// async global->LDS, 16B per lane; dest = wave-uniform base + lane*16
__device__ __forceinline__ void glds16(const unsigned short* g, unsigned short* l) {
    __builtin_amdgcn_global_load_lds(
        (const __attribute__((address_space(1))) unsigned int*)g,
        (__attribute__((address_space(3))) unsigned int*)l, 16, 0, 0);
}

// ---------------- prep: cast x->bf16  +  4 weight transposes (fp32 KxN -> bf16 NxK) ---------
__global__ __launch_bounds__(256) void prep(const float* __restrict__ x,
                                            const float* __restrict__ Wq,
                                            const float* __restrict__ Wk,
                                            const float* __restrict__ Wv,
                                            const float* __restrict__ Wo,
                                            unsigned short* __restrict__ xb,
                                            unsigned short* __restrict__ Wt,
                                            unsigned short* __restrict__ Wot) {
    int bid = blockIdx.x;
    int tid = threadIdx.x;
    if (bid < 4096) {  // cast: 1M float4
        int i = bid * 256 + tid;
        float4 v = *(const float4*)(x + (size_t)i * 4);
        unsigned short o[4] = {f2bf(v.x), f2bf(v.y), f2bf(v.z), f2bf(v.w)};
        *(unsigned long long*)(xb + (size_t)i * 4) = *(unsigned long long*)o;
        return;
    }
    bid -= 4096;
    const float* W; unsigned short* D; int K, N;
    if (bid < 512)       { W = Wq; D = Wt;                          K = 1024; N = 2048; }
    else if (bid < 768)  { bid -= 512;  W = Wk; D = Wt + (size_t)2048 * 1024; K = 1024; N = 1024; }
    else if (bid < 1024) { bid -= 768;  W = Wv; D = Wt + (size_t)3072 * 1024; K = 1024; N = 1024; }
    else                 { bid -= 1024; W = Wo; D = Wot;                      K = 2048; N = 1024; }
    __shared__ __attribute__((aligned(16))) unsigned short Ls[64 * 72];
    int ntiles = N >> 6;
    int kt = bid / ntiles, nt = bid - kt * ntiles;
    int k0 = kt * 64, n0 = nt * 64;
    for (int t = 0; t < 4; t++) {
        int idx = tid + t * 256;
        int r = idx >> 4, seg = idx & 15;
        float4 v = *(const float4*)(W + (size_t)(k0 + r) * N + n0 + seg * 4);
        int c = seg * 4;
        Ls[(c + 0) * 72 + r] = f2bf(v.x);
        Ls[(c + 1) * 72 + r] = f2bf(v.y);
        Ls[(c + 2) * 72 + r] = f2bf(v.z);
        Ls[(c + 3) * 72 + r] = f2bf(v.w);
    }
    __syncthreads();
    for (int t = 0; t < 2; t++) {
        int idx = tid + t * 256;
        int rr = idx >> 3, seg = idx & 7;
        uint4v v = *(const uint4v*)(Ls + rr * 72 + seg * 8);
        *(uint4v*)(D + (size_t)(n0 + rr) * K + k0 + seg * 8) = v;
    }
}

// ---------------- GEMM (QKV): C[M,N] = A[M,K](bf16) @ Bt[N,K]^T(bf16), BK=32 ----------------
template <int OUT_BF16, int BN>
__global__ __launch_bounds__(256) void gemm_bt(const unsigned short* __restrict__ A,
                                               const unsigned short* __restrict__ Bt,
                                               void* __restrict__ Cout,
                                               int M, int N, int K) {
    constexpr int MT = (BN == 128) ? 4 : 2;
    __shared__ __attribute__((aligned(16))) unsigned short As[2][128 * 32];
    __shared__ __attribute__((aligned(16))) unsigned short Bs[2][BN * 32];
    const int tid = threadIdx.x;
    const int lane = tid & 63;
    const int warp = tid >> 6;
    const int ln = lane & 15;
    const int quad = lane >> 4;
    const int wm = (BN == 128) ? (warp >> 1) : warp;
    const int wn = (BN == 128) ? (warp & 1) : 0;
    const int m0 = blockIdx.y * 128;
    const int n0 = blockIdx.x * BN;

    const int srow = lane >> 2;
    const int schunk = (lane & 3) ^ (srow & 3);
    const unsigned short* Ag = A + (size_t)(m0 + warp * 16 + srow) * K + schunk * 8;
    const unsigned short* Bg = Bt + (size_t)(n0 + warp * 16 + srow) * K + schunk * 8;

    f32x4 acc[MT][4];
#pragma unroll
    for (int i = 0; i < MT; i++)
#pragma unroll
        for (int j = 0; j < 4; j++) acc[i][j] = (f32x4){0.f, 0.f, 0.f, 0.f};

    auto stage = [&](int k0, int bi) {
        glds16(Ag + k0, As[bi] + warp * 16 * 32);
        glds16(Ag + (size_t)64 * K + k0, As[bi] + warp * 16 * 32 + 64 * 32);
        glds16(Bg + k0, Bs[bi] + warp * 16 * 32);
        if (BN == 128) glds16(Bg + (size_t)64 * K + k0, Bs[bi] + warp * 16 * 32 + 64 * 32);
    };

    const int rq = quad ^ (ln & 3);   // swizzled read chunk
    const int KI = K >> 5;
    stage(0, 0);
    for (int it = 0; it < KI; it++) {
        __syncthreads();            // drains my glds for buf it&1
        if (it + 1 < KI) stage((it + 1) << 5, (it + 1) & 1);
        const unsigned short* Ab = As[it & 1];
        const unsigned short* Bb = Bs[it & 1];
        short8 af[MT], bf[4];
#pragma unroll
        for (int mt = 0; mt < MT; mt++)
            af[mt] = *(const short8*)(Ab + (wm * (MT * 16) + mt * 16 + ln) * 32 + rq * 8);
#pragma unroll
        for (int nt = 0; nt < 4; nt++)
            bf[nt] = *(const short8*)(Bb + (wn * 64 + nt * 16 + ln) * 32 + rq * 8);
#pragma unroll
        for (int mt = 0; mt < MT; mt++)
#pragma unroll
            for (int nt = 0; nt < 4; nt++)
                acc[mt][nt] = __builtin_amdgcn_mfma_f32_16x16x32_bf16(bf[nt], af[mt], acc[mt][nt], 0, 0, 0);
    }
#pragma unroll
    for (int mt = 0; mt < MT; mt++) {
        int row = m0 + wm * (MT * 16) + mt * 16 + ln;
#pragma unroll
        for (int nt = 0; nt < 4; nt++) {
            int colb = n0 + wn * 64 + nt * 16 + quad * 4;
            if (OUT_BF16) {
                unsigned long long pk =
                    (unsigned long long)cvtpk(acc[mt][nt][0], acc[mt][nt][1]) |
                    ((unsigned long long)cvtpk(acc[mt][nt][2], acc[mt][nt][3]) << 32);
                *(unsigned long long*)((unsigned short*)Cout + (size_t)row * N + colb) = pk;
            } else {
                *(f32x4*)((float*)Cout + (size_t)row * N + colb) = acc[mt][nt];
            }
        }
    }
}

// ---------------- GEMM (O-proj): BM=128, BN=64, BK=64 -- half the barriers of BK=32 ----------
// Same staging idiom extended to 8 chunks/row: LDS[row][pos] holds logical chunk pos^(row&7);
// glds dest is linear (lane -> row=l>>3, pos=l&7), so global src chunk = (l&7)^(l>>3).
// Read: rc = (ks*4+quad)^(ln&7) retrieves logical chunk ks*4+quad at row frag*16+ln.
__global__ __launch_bounds__(256) void gemm_o(const unsigned short* __restrict__ A,
                                              const unsigned short* __restrict__ Bt,
                                              float* __restrict__ Cout,
                                              int M, int N, int K) {
    __shared__ __attribute__((aligned(16))) unsigned short As[2][128 * 64];  // 32 KB
    __shared__ __attribute__((aligned(16))) unsigned short Bs[2][64 * 64];   // 16 KB
    const int tid = threadIdx.x;
    const int lane = tid & 63;
    const int warp = tid >> 6;
    const int ln = lane & 15;
    const int quad = lane >> 4;
    const int m0 = blockIdx.y * 128;
    const int n0 = blockIdx.x * 64;

    const int srow = lane >> 3;            // 0..7
    const int schunk = (lane & 7) ^ srow;  // inverse-swizzled source chunk
    const unsigned short* Ag = A + (size_t)(m0 + warp * 32 + srow) * K + schunk * 8;
    const unsigned short* Bg = Bt + (size_t)(n0 + warp * 16 + srow) * K + schunk * 8;

    f32x4 acc[2][4];
#pragma unroll
    for (int i = 0; i < 2; i++)
#pragma unroll
        for (int j = 0; j < 4; j++) acc[i][j] = (f32x4){0.f, 0.f, 0.f, 0.f};

    auto stage = [&](int k0, int bi) {
#pragma unroll
        for (int g = 0; g < 4; g++)   // A rows warp*32 + g*8 + srow
            glds16(Ag + (size_t)(g * 8) * K + k0, As[bi] + (warp * 32 + g * 8) * 64);
#pragma unroll
        for (int g = 0; g < 2; g++)   // B rows warp*16 + g*8 + srow
            glds16(Bg + (size_t)(g * 8) * K + k0, Bs[bi] + (warp * 16 + g * 8) * 64);
    };

    const int KI = K >> 6;
    stage(0, 0);
    for (int it = 0; it < KI; it++) {
        __syncthreads();            // drains my glds for buf it&1
        if (it + 1 < KI) stage((it + 1) << 6, (it + 1) & 1);
        const unsigned short* Ab = As[it & 1];
        const unsigned short* Bb = Bs[it & 1];
#pragma unroll
        for (int ks = 0; ks < 2; ks++) {
            const int rc = ((ks << 2) + quad) ^ (ln & 7);
            short8 af[2], bf[4];
#pragma unroll
            for (int mt = 0; mt < 2; mt++)
                af[mt] = *(const short8*)(Ab + (warp * 32 + mt * 16 + ln) * 64 + rc * 8);
#pragma unroll
            for (int nt = 0; nt < 4; nt++)
                bf[nt] = *(const short8*)(Bb + (nt * 16 + ln) * 64 + rc * 8);
#pragma unroll
            for (int mt = 0; mt < 2; mt++)
#pragma unroll
                for (int nt = 0; nt < 4; nt++)
                    acc[mt][nt] = __builtin_amdgcn_mfma_f32_16x16x32_bf16(bf[nt], af[mt], acc[mt][nt], 0, 0, 0);
        }
    }
#pragma unroll
    for (int mt = 0; mt < 2; mt++) {
        int row = m0 + warp * 32 + mt * 16 + ln;
#pragma unroll
        for (int nt = 0; nt < 4; nt++) {
            int colb = n0 + nt * 16 + quad * 4;
            *(f32x4*)(Cout + (size_t)row * N + colb) = acc[mt][nt];
        }
    }
}

// ---------------- fused norm_rope (blocks < 24576) + v_transpose (rest) ----------------
// Q additionally pre-scaled by (1/sqrt(128))*log2(e) so attn's QK^T lands directly in
// the exp2 domain.
__global__ __launch_bounds__(256) void nrvt(const unsigned short* __restrict__ QKV,
                                            const float* __restrict__ qw,
                                            const float* __restrict__ kw,
                                            unsigned short* __restrict__ Q,
                                            unsigned short* __restrict__ Kb,
                                            unsigned short* __restrict__ Vt) {
    if (blockIdx.x < 24576) {
        int warp = threadIdx.x >> 6;
        int lane = threadIdx.x & 63;
        int gid = blockIdx.x * 4 + warp;
        int tok = gid / 24;
        int slot = gid - tok * 24;
        int b = tok >> 11, t = tok & 2047;
        const float* w;
        unsigned short* dst;
        int col0;
        float sc;
        if (slot < 16) {
            col0 = slot * HD;
            dst = Q + ((size_t)(b * 16 + slot) * TSEQ + t) * HD;
            w = qw;
            sc = 0.12750580997495268f;  // (1/sqrt(128)) * log2(e) folded into Q
        } else {
            int hk = slot - 16;
            col0 = QOUT + hk * HD;
            dst = Kb + ((size_t)(b * 8 + hk) * TSEQ + t) * HD;
            w = kw;
            sc = 1.0f;
        }
        const unsigned short* row = QKV + (size_t)tok * 4096 + col0;
        float e0 = bf2f(row[lane]), e1 = bf2f(row[lane + 64]);
        float ss = e0 * e0 + e1 * e1;
        for (int off = 1; off < 64; off <<= 1) ss += __shfl_xor(ss, off);
        float rr = rsqrtf(ss * (1.0f / 128.0f) + 1e-6f);
        float n0 = e0 * rr * w[lane];
        float n1 = e1 * rr * w[lane + 64];
        float invf = __builtin_exp2f(-(float)lane * 0.20762050593045951f);
        float ang = (float)t * invf;
        float sf, cf;
        __sincosf(ang, &sf, &cf);
        dst[lane] = f2bf((n0 * cf - n1 * sf) * sc);
        dst[lane + 64] = f2bf((n1 * cf + n0 * sf) * sc);
        return;
    }
    // v_transpose
    __shared__ __attribute__((aligned(16))) unsigned short Ls[128 * 72];
    int bid = blockIdx.x - 24576;
    int tt = bid & 31, hk = (bid >> 5) & 7, b = bid >> 8;
    int t0 = tt * 64;
    int tid = threadIdx.x;
    const unsigned short* base = QKV + (size_t)(b * 2048 + t0) * 4096 + 3072 + hk * 128;
    for (int i = 0; i < 4; i++) {
        int idx = tid + i * 256;
        int r = idx >> 4, seg = idx & 15;
        uint4v v = *(const uint4v*)(base + (size_t)r * 4096 + seg * 8);
        unsigned short* pv = (unsigned short*)&v;
        int d = seg * 8;
        for (int jj = 0; jj < 8; jj++) Ls[(d + jj) * 72 + r] = pv[jj];
    }
    __syncthreads();
    unsigned short* out = Vt + (size_t)(b * 8 + hk) * 128 * 2048;
    for (int i = 0; i < 4; i++) {
        int idx = tid + i * 256;
        int d = idx >> 3, seg = idx & 7;
        uint4v v = *(const uint4v*)(Ls + d * 72 + seg * 8);
        *(uint4v*)(out + (size_t)d * 2048 + t0 + seg * 8) = v;
    }
}

// ---------------- flash attention v9: load-balanced p + strip1-first + deferred lac ---------
// grid (16 px, 32 b*h). p = (b==0) ? px : 15-px, so dispatch ids c and c+256 (same CU on the
// 2-sweep round-robin) carry loop counts (32-p) and (17+p): every CU gets exactly 49
// block-iters -- removes the ~30% tail that held OccupancyPercent at 17% (ideal 25%).
// Softmax processes strip 1 (always active) first so pf[1]'s LDS read retires under strip 0's
// softmax VALU; the 4 row-sum lac MFMAs move after the PV loop so nothing consumes a pf
// fragment immediately after its ds_read.
__global__ __launch_bounds__(256, 2) void attn(const unsigned short* __restrict__ Q,
                                               const unsigned short* __restrict__ Kg,
                                               const unsigned short* __restrict__ Vt,
                                               unsigned short* __restrict__ Og) {
    __shared__ __attribute__((aligned(16))) unsigned short Ks[2][64 * 128];  // swizzled (kv, d)
    __shared__ __attribute__((aligned(16))) unsigned short Vs[2][128 * 64];  // swizzled (d, kv)
    __shared__ __attribute__((aligned(16))) unsigned short Ps[4][16 * 72];
    const int bh = blockIdx.y;
    const int b = bh >> 4, h = bh & 15, hk = h >> 1;
    const int p = (b == 0) ? (int)blockIdx.x : (15 - (int)blockIdx.x);
    const int tid = threadIdx.x;
    const int warp = tid >> 6, lane = tid & 63, ln = lane & 15, quad = lane >> 4;
    const int strip[2] = { p * 64 + warp * 16, (31 - p) * 64 + warp * 16 };
    const int jdiag[2] = { p, 31 - p };

    const unsigned short* Kbase = Kg + (size_t)(b * 8 + hk) * TSEQ * HD;
    const unsigned short* Vbase = Vt + (size_t)(b * 8 + hk) * HD * TSEQ;
    const unsigned short* Qh = Q + (size_t)(b * 16 + h) * TSEQ * HD;

    short8 qf[2][4];
#pragma unroll
    for (int st = 0; st < 2; st++)
#pragma unroll
        for (int kt = 0; kt < 4; kt++)
            qf[st][kt] = *(const short8*)(Qh + (size_t)(strip[st] + ln) * HD + kt * 32 + quad * 8);

    f32x4 o[2][8];
    f32x4 lac[2];
#pragma unroll
    for (int st = 0; st < 2; st++) {
        lac[st] = (f32x4){0.f, 0.f, 0.f, 0.f};
#pragma unroll
        for (int ot = 0; ot < 8; ot++) o[st][ot] = (f32x4){0.f, 0.f, 0.f, 0.f};
    }
    float m_[2] = {-1e30f, -1e30f};

    const int kr = lane >> 4;
    const int kc = lane & 15;
    const int vr = lane >> 3;
    const int vc = lane & 7;

    auto stage_kv = [&](int jt, int bi) {
        const int j0s = jt * 64;
        unsigned short* KsB = Ks[bi];
        unsigned short* VsB = Vs[bi];
#pragma unroll
        for (int c = 0; c < 4; c++) {   // K: LDS[r][c] = K[r][c ^ (r&15)]
            int row = warp * 16 + c * 4 + kr;
            glds16(Kbase + (size_t)(j0s + row) * HD + ((kc ^ (row & 15)) * 8),
                   KsB + (warp * 16 + c * 4) * 128);
        }
#pragma unroll
        for (int c = 0; c < 4; c++) {   // V^T: LDS[d][c] = V[d][c ^ (d&7)]
            int d = warp * 32 + c * 8 + vr;
            glds16(Vbase + (size_t)d * TSEQ + j0s + ((vc ^ (d & 7)) * 8),
                   VsB + (warp * 32 + c * 8) * 64);
        }
    };

    // bf16 1.0 fragment for row-sum MFMA (B = all-ones 16x32)
    short8 ones8;
#pragma unroll
    for (int i = 0; i < 8; i++) ones8[i] = (short)0x3F80;

    const int nT = 32 - p;
    stage_kv(0, 0);
    for (int j = 0; j < nT; j++) {
        __syncthreads();                 // drains my glds for buf j&1 (prev iter's prefetch)
        if (j + 1 < nT) stage_kv(j + 1, (j + 1) & 1);
        const unsigned short* KsC = Ks[j & 1];
        const unsigned short* VsC = Vs[j & 1];
        const bool act0 = (j <= jdiag[0]);
        // ---- QK^T for both strips, kf shared (Q pre-scaled: s is in exp2 domain) ----
        f32x4 s[2][4];
#pragma unroll
        for (int kb = 0; kb < 4; kb++) {
            s[0][kb] = (f32x4){0.f, 0.f, 0.f, 0.f};
            s[1][kb] = (f32x4){0.f, 0.f, 0.f, 0.f};
        }
        __builtin_amdgcn_s_setprio(1);
#pragma unroll
        for (int kt = 0; kt < 4; kt++) {
            short8 kf[4];
#pragma unroll
            for (int kb = 0; kb < 4; kb++)
                kf[kb] = *(const short8*)(KsC + (kb * 16 + ln) * 128 + (((kt * 4 + quad) ^ ln) * 8));
#pragma unroll
            for (int kb = 0; kb < 4; kb++)
                s[1][kb] = __builtin_amdgcn_mfma_f32_16x16x32_bf16(kf[kb], qf[1][kt], s[1][kb], 0, 0, 0);
            if (act0)
#pragma unroll
                for (int kb = 0; kb < 4; kb++)
                    s[0][kb] = __builtin_amdgcn_mfma_f32_16x16x32_bf16(kf[kb], qf[0][kt], s[0][kb], 0, 0, 0);
        }
        __builtin_amdgcn_s_setprio(0);
        // ---- softmax + P staging, strip 1 first: defer-max (THR=8), shuffle-free common path
        short8 pf[2][2];
        bool needR[2] = {false, false};
        float alpha[2] = {1.f, 1.f};
#pragma unroll
        for (int sti = 0; sti < 2; sti++) {
            const int st = 1 - sti;
            if (st == 0 && !act0) continue;
            float mk[4];
            if (j == jdiag[st]) {
                const int qloc = warp * 16 + ln;
#pragma unroll
                for (int kb = 0; kb < 4; kb++) {
#pragma unroll
                    for (int r = 0; r < 4; r++) {
                        int kvloc = kb * 16 + quad * 4 + r;
                        if (kvloc > qloc) s[st][kb][r] = -1e30f;
                    }
                    mk[kb] = fmaxf(fmaxf(s[st][kb][0], s[st][kb][1]),
                                   fmaxf(s[st][kb][2], s[st][kb][3]));
                }
            } else {
#pragma unroll
                for (int kb = 0; kb < 4; kb++)
                    mk[kb] = fmaxf(fmaxf(s[st][kb][0], s[st][kb][1]),
                                   fmaxf(s[st][kb][2], s[st][kb][3]));
            }
            float mx = fmaxf(fmaxf(mk[0], mk[1]), fmaxf(mk[2], mk[3]));
            float mn = m_[st];
            // lane-local max is a lower bound on the row max; if every lane is within
            // THR=8 of m, the row max is too -> keep m (P bounded by 2^8, bf16-safe).
            if (!__all(mx <= mn + 8.0f)) {
                mx = fmaxf(mx, __shfl_xor(mx, 16));
                mx = fmaxf(mx, __shfl_xor(mx, 32));
                mn = fmaxf(m_[st], mx);
                alpha[st] = __builtin_exp2f(m_[st] - mn);
                m_[st] = mn;
                needR[st] = true;
            }
#pragma unroll
            for (int kb = 0; kb < 4; kb++) {
                float p0 = __builtin_exp2f(s[st][kb][0] - mn);
                float p1 = __builtin_exp2f(s[st][kb][1] - mn);
                float p2 = __builtin_exp2f(s[st][kb][2] - mn);
                float p3 = __builtin_exp2f(s[st][kb][3] - mn);
                unsigned long long pk =
                    (unsigned long long)cvtpk(p0, p1) |
                    ((unsigned long long)cvtpk(p2, p3) << 32);
                *(unsigned long long*)(&Ps[warp][ln * 72 + kb * 16 + quad * 4]) = pk;
            }
            pf[st][0] = *(const short8*)(&Ps[warp][ln * 72 + quad * 8]);
            pf[st][1] = *(const short8*)(&Ps[warp][ln * 72 + 32 + quad * 8]);
        }
        // ---- rescale O and l (uniform branch, rare after first tile) ----
        if (act0 && needR[0]) {
            float a = alpha[0];
#pragma unroll
            for (int ot = 0; ot < 8; ot++)
#pragma unroll
                for (int r = 0; r < 4; r++) o[0][ot][r] *= a;
#pragma unroll
            for (int r = 0; r < 4; r++) lac[0][r] *= a;
        }
        if (needR[1]) {
            float a = alpha[1];
#pragma unroll
            for (int ot = 0; ot < 8; ot++)
#pragma unroll
                for (int r = 0; r < 4; r++) o[1][ot][r] *= a;
#pragma unroll
            for (int r = 0; r < 4; r++) lac[1][r] *= a;
        }
        // ---- PV, vf shared across strips; operand-swapped (O: col=q=ln, rows=d) ----
        __builtin_amdgcn_s_setprio(1);
#pragma unroll
        for (int ot = 0; ot < 8; ot++) {
            short8 vf0 = *(const short8*)(VsC + (ot * 16 + ln) * 64 + ((quad ^ (ln & 7)) * 8));
            short8 vf1 = *(const short8*)(VsC + (ot * 16 + ln) * 64 + (((4 + quad) ^ (ln & 7)) * 8));
            o[1][ot] = __builtin_amdgcn_mfma_f32_16x16x32_bf16(vf0, pf[1][0], o[1][ot], 0, 0, 0);
            o[1][ot] = __builtin_amdgcn_mfma_f32_16x16x32_bf16(vf1, pf[1][1], o[1][ot], 0, 0, 0);
            if (act0) {
                o[0][ot] = __builtin_amdgcn_mfma_f32_16x16x32_bf16(vf0, pf[0][0], o[0][ot], 0, 0, 0);
                o[0][ot] = __builtin_amdgcn_mfma_f32_16x16x32_bf16(vf1, pf[0][1], o[0][ot], 0, 0, 0);
            }
        }
        // ---- row-sum l via MFMA against ones (deferred: pf long since resolved) ----
        lac[1] = __builtin_amdgcn_mfma_f32_16x16x32_bf16(ones8, pf[1][0], lac[1], 0, 0, 0);
        lac[1] = __builtin_amdgcn_mfma_f32_16x16x32_bf16(ones8, pf[1][1], lac[1], 0, 0, 0);
        if (act0) {
            lac[0] = __builtin_amdgcn_mfma_f32_16x16x32_bf16(ones8, pf[0][0], lac[0], 0, 0, 0);
            lac[0] = __builtin_amdgcn_mfma_f32_16x16x32_bf16(ones8, pf[0][1], lac[0], 0, 0, 0);
        }
        __builtin_amdgcn_s_setprio(0);
    }
    // epilogue: lane has q = strip+ln; regs are 4 consecutive d -> 8B stores
#pragma unroll
    for (int st = 0; st < 2; st++) {
        float inv = 1.0f / lac[st][0];
        size_t rowoff = ((size_t)(b * TSEQ + strip[st] + ln)) * QOUT + h * 128 + quad * 4;
#pragma unroll
        for (int ot = 0; ot < 8; ot++) {
            unsigned long long pk =
                (unsigned long long)cvtpk(o[st][ot][0] * inv, o[st][ot][1] * inv) |
                ((unsigned long long)cvtpk(o[st][ot][2] * inv, o[st][ot][3] * inv) << 32);
            *(unsigned long long*)(Og + rowoff + ot * 16) = pk;
        }
    }
}

extern "C" void kernel_launch(void* const* d_in, const int* in_sizes, int n_in,
                              void* d_out, int out_size, void* d_ws, size_t ws_size,
                              hipStream_t stream) {
    (void)in_sizes; (void)n_in; (void)out_size;
    const float* x  = (const float*)d_in[0];
    const float* Wq = (const float*)d_in[1];
    const float* Wk = (const float*)d_in[2];
    const float* Wv = (const float*)d_in[3];
    const float* Wo = (const float*)d_in[4];
    const float* qw = (const float*)d_in[5];
    const float* kw = (const float*)d_in[6];

    char* ws = (char*)d_ws;
    const size_t MB = 1024 * 1024;
    unsigned short* Wt   = (unsigned short*)(ws);            // 8 MB
    unsigned short* Wot  = (unsigned short*)(ws + 8 * MB);   // 4 MB
    unsigned short* QKVb = (unsigned short*)(ws + 12 * MB);  // 32 MB (bf16)
    unsigned short* xb   = (unsigned short*)(ws + 44 * MB);  // 8 MB
    unsigned short* Qb   = (unsigned short*)(ws + 52 * MB);  // 16 MB
    unsigned short* Kb   = (unsigned short*)(ws + 68 * MB);  // 8 MB
    unsigned short* Vtb  = (unsigned short*)(ws + 76 * MB);  // 8 MB
    unsigned short* Ob   = (unsigned short*)(ws + 84 * MB);  // 16 MB
    if (ws_size < 100 * MB) return;

    prep<<<dim3(5632), 256, 0, stream>>>(x, Wq, Wk, Wv, Wo, xb, Wt, Wot);
    gemm_bt<1, 128><<<dim3(32, 32), 256, 0, stream>>>(xb, Wt, QKVb, 4096, 4096, 1024);
    nrvt<<<dim3(25088), 256, 0, stream>>>(QKVb, qw, kw, Qb, Kb, Vtb);
    attn<<<dim3(16, 32), 256, 0, stream>>>(Qb, Kb, Vtb, Ob);
    gemm_o<<<dim3(16, 32), 256, 0, stream>>>(Ob, Wot, (float*)d_out, 4096, 1024, 2048);
}

// Round 3
// 261.110 us; speedup vs baseline: 1.0932x; 1.0057x over previous
//
#include <hip/hip_runtime.h>
#include <math.h>

typedef __attribute__((ext_vector_type(8))) short short8;
typedef __attribute__((ext_vector_type(4))) float f32x4;
typedef __attribute__((ext_vector_type(4))) unsigned int uint4v;

#define HIDDEN 1024
#define QOUT 2048
#define KVOUT 1024
#define HD 128
#define TSEQ 2048

__device__ __forceinline__ float bf2f(unsigned short h) {
    union { unsigned int u; float f; } x; x.u = ((unsigned int)h) << 16; return x.f;
}
__device__ __forceinline__ unsigned short f2bf(float f) {
    union { float f; unsigned int u; } x; x.f = f;
    unsigned int r = (x.u + 0x7fffu + ((x.u >> 16) & 1u)) >> 16;
    return (unsigned short)r;
}
// HW packed f32->bf16 (RNE, same semantics as f2bf pair) -- 1 VALU op per 2 values
__device__ __forceinline__ unsigned int cvtpk(float lo, float hi) {
    unsigned int r;
    asm("v_cvt_pk_bf16_f32 %0, %1, %2" : "=v"(r) : "v"(lo), "v"(hi));
    return r;
}

// async global->LDS, 16B per lane; dest = wave-uniform base + lane*16
__device__ __forceinline__ void glds16(const unsigned short* g, unsigned short* l) {
    __builtin_amdgcn_global_load_lds(
        (const __attribute__((address_space(1))) unsigned int*)g,
        (__attribute__((address_space(3))) unsigned int*)l, 16, 0, 0);
}

// ---------------- prep: cast x->bf16  +  4 weight transposes (fp32 KxN -> bf16 NxK) ---------
__global__ __launch_bounds__(256) void prep(const float* __restrict__ x,
                                            const float* __restrict__ Wq,
                                            const float* __restrict__ Wk,
                                            const float* __restrict__ Wv,
                                            const float* __restrict__ Wo,
                                            unsigned short* __restrict__ xb,
                                            unsigned short* __restrict__ Wt,
                                            unsigned short* __restrict__ Wot) {
    int bid = blockIdx.x;
    int tid = threadIdx.x;
    if (bid < 4096) {  // cast: 1M float4
        int i = bid * 256 + tid;
        float4 v = *(const float4*)(x + (size_t)i * 4);
        unsigned short o[4] = {f2bf(v.x), f2bf(v.y), f2bf(v.z), f2bf(v.w)};
        *(unsigned long long*)(xb + (size_t)i * 4) = *(unsigned long long*)o;
        return;
    }
    bid -= 4096;
    const float* W; unsigned short* D; int K, N;
    if (bid < 512)       { W = Wq; D = Wt;                          K = 1024; N = 2048; }
    else if (bid < 768)  { bid -= 512;  W = Wk; D = Wt + (size_t)2048 * 1024; K = 1024; N = 1024; }
    else if (bid < 1024) { bid -= 768;  W = Wv; D = Wt + (size_t)3072 * 1024; K = 1024; N = 1024; }
    else                 { bid -= 1024; W = Wo; D = Wot;                      K = 2048; N = 1024; }
    __shared__ __attribute__((aligned(16))) unsigned short Ls[64 * 72];
    int ntiles = N >> 6;
    int kt = bid / ntiles, nt = bid - kt * ntiles;
    int k0 = kt * 64, n0 = nt * 64;
    for (int t = 0; t < 4; t++) {
        int idx = tid + t * 256;
        int r = idx >> 4, seg = idx & 15;
        float4 v = *(const float4*)(W + (size_t)(k0 + r) * N + n0 + seg * 4);
        int c = seg * 4;
        Ls[(c + 0) * 72 + r] = f2bf(v.x);
        Ls[(c + 1) * 72 + r] = f2bf(v.y);
        Ls[(c + 2) * 72 + r] = f2bf(v.z);
        Ls[(c + 3) * 72 + r] = f2bf(v.w);
    }
    __syncthreads();
    for (int t = 0; t < 2; t++) {
        int idx = tid + t * 256;
        int rr = idx >> 3, seg = idx & 7;
        uint4v v = *(const uint4v*)(Ls + rr * 72 + seg * 8);
        *(uint4v*)(D + (size_t)(n0 + rr) * K + k0 + seg * 8) = v;
    }
}

// ---------------- GEMM (QKV): C[M,N] = A[M,K](bf16) @ Bt[N,K]^T(bf16), BK=32 ----------------
template <int OUT_BF16, int BN>
__global__ __launch_bounds__(256) void gemm_bt(const unsigned short* __restrict__ A,
                                               const unsigned short* __restrict__ Bt,
                                               void* __restrict__ Cout,
                                               int M, int N, int K) {
    constexpr int MT = (BN == 128) ? 4 : 2;
    __shared__ __attribute__((aligned(16))) unsigned short As[2][128 * 32];
    __shared__ __attribute__((aligned(16))) unsigned short Bs[2][BN * 32];
    const int tid = threadIdx.x;
    const int lane = tid & 63;
    const int warp = tid >> 6;
    const int ln = lane & 15;
    const int quad = lane >> 4;
    const int wm = (BN == 128) ? (warp >> 1) : warp;
    const int wn = (BN == 128) ? (warp & 1) : 0;
    const int m0 = blockIdx.y * 128;
    const int n0 = blockIdx.x * BN;

    const int srow = lane >> 2;
    const int schunk = (lane & 3) ^ (srow & 3);
    const unsigned short* Ag = A + (size_t)(m0 + warp * 16 + srow) * K + schunk * 8;
    const unsigned short* Bg = Bt + (size_t)(n0 + warp * 16 + srow) * K + schunk * 8;

    f32x4 acc[MT][4];
#pragma unroll
    for (int i = 0; i < MT; i++)
#pragma unroll
        for (int j = 0; j < 4; j++) acc[i][j] = (f32x4){0.f, 0.f, 0.f, 0.f};

    auto stage = [&](int k0, int bi) {
        glds16(Ag + k0, As[bi] + warp * 16 * 32);
        glds16(Ag + (size_t)64 * K + k0, As[bi] + warp * 16 * 32 + 64 * 32);
        glds16(Bg + k0, Bs[bi] + warp * 16 * 32);
        if (BN == 128) glds16(Bg + (size_t)64 * K + k0, Bs[bi] + warp * 16 * 32 + 64 * 32);
    };

    const int rq = quad ^ (ln & 3);   // swizzled read chunk
    const int KI = K >> 5;
    stage(0, 0);
    for (int it = 0; it < KI; it++) {
        __syncthreads();            // drains my glds for buf it&1
        if (it + 1 < KI) stage((it + 1) << 5, (it + 1) & 1);
        const unsigned short* Ab = As[it & 1];
        const unsigned short* Bb = Bs[it & 1];
        short8 af[MT], bf[4];
#pragma unroll
        for (int mt = 0; mt < MT; mt++)
            af[mt] = *(const short8*)(Ab + (wm * (MT * 16) + mt * 16 + ln) * 32 + rq * 8);
#pragma unroll
        for (int nt = 0; nt < 4; nt++)
            bf[nt] = *(const short8*)(Bb + (wn * 64 + nt * 16 + ln) * 32 + rq * 8);
#pragma unroll
        for (int mt = 0; mt < MT; mt++)
#pragma unroll
            for (int nt = 0; nt < 4; nt++)
                acc[mt][nt] = __builtin_amdgcn_mfma_f32_16x16x32_bf16(bf[nt], af[mt], acc[mt][nt], 0, 0, 0);
    }
#pragma unroll
    for (int mt = 0; mt < MT; mt++) {
        int row = m0 + wm * (MT * 16) + mt * 16 + ln;
#pragma unroll
        for (int nt = 0; nt < 4; nt++) {
            int colb = n0 + wn * 64 + nt * 16 + quad * 4;
            if (OUT_BF16) {
                unsigned long long pk =
                    (unsigned long long)cvtpk(acc[mt][nt][0], acc[mt][nt][1]) |
                    ((unsigned long long)cvtpk(acc[mt][nt][2], acc[mt][nt][3]) << 32);
                *(unsigned long long*)((unsigned short*)Cout + (size_t)row * N + colb) = pk;
            } else {
                *(f32x4*)((float*)Cout + (size_t)row * N + colb) = acc[mt][nt];
            }
        }
    }
}

// ---------------- GEMM (O-proj): BM=128, BN=64, BK=64 -- half the barriers of BK=32 ----------
// Same staging idiom extended to 8 chunks/row: LDS[row][pos] holds logical chunk pos^(row&7);
// glds dest is linear (lane -> row=l>>3, pos=l&7), so global src chunk = (l&7)^(l>>3).
// Read: rc = (ks*4+quad)^(ln&7) retrieves logical chunk ks*4+quad at row frag*16+ln.
__global__ __launch_bounds__(256) void gemm_o(const unsigned short* __restrict__ A,
                                              const unsigned short* __restrict__ Bt,
                                              float* __restrict__ Cout,
                                              int M, int N, int K) {
    __shared__ __attribute__((aligned(16))) unsigned short As[2][128 * 64];  // 32 KB
    __shared__ __attribute__((aligned(16))) unsigned short Bs[2][64 * 64];   // 16 KB
    const int tid = threadIdx.x;
    const int lane = tid & 63;
    const int warp = tid >> 6;
    const int ln = lane & 15;
    const int quad = lane >> 4;
    const int m0 = blockIdx.y * 128;
    const int n0 = blockIdx.x * 64;

    const int srow = lane >> 3;            // 0..7
    const int schunk = (lane & 7) ^ srow;  // inverse-swizzled source chunk
    const unsigned short* Ag = A + (size_t)(m0 + warp * 32 + srow) * K + schunk * 8;
    const unsigned short* Bg = Bt + (size_t)(n0 + warp * 16 + srow) * K + schunk * 8;

    f32x4 acc[2][4];
#pragma unroll
    for (int i = 0; i < 2; i++)
#pragma unroll
        for (int j = 0; j < 4; j++) acc[i][j] = (f32x4){0.f, 0.f, 0.f, 0.f};

    auto stage = [&](int k0, int bi) {
#pragma unroll
        for (int g = 0; g < 4; g++)   // A rows warp*32 + g*8 + srow
            glds16(Ag + (size_t)(g * 8) * K + k0, As[bi] + (warp * 32 + g * 8) * 64);
#pragma unroll
        for (int g = 0; g < 2; g++)   // B rows warp*16 + g*8 + srow
            glds16(Bg + (size_t)(g * 8) * K + k0, Bs[bi] + (warp * 16 + g * 8) * 64);
    };

    const int KI = K >> 6;
    stage(0, 0);
    for (int it = 0; it < KI; it++) {
        __syncthreads();            // drains my glds for buf it&1
        if (it + 1 < KI) stage((it + 1) << 6, (it + 1) & 1);
        const unsigned short* Ab = As[it & 1];
        const unsigned short* Bb = Bs[it & 1];
#pragma unroll
        for (int ks = 0; ks < 2; ks++) {
            const int rc = ((ks << 2) + quad) ^ (ln & 7);
            short8 af[2], bf[4];
#pragma unroll
            for (int mt = 0; mt < 2; mt++)
                af[mt] = *(const short8*)(Ab + (warp * 32 + mt * 16 + ln) * 64 + rc * 8);
#pragma unroll
            for (int nt = 0; nt < 4; nt++)
                bf[nt] = *(const short8*)(Bb + (nt * 16 + ln) * 64 + rc * 8);
#pragma unroll
            for (int mt = 0; mt < 2; mt++)
#pragma unroll
                for (int nt = 0; nt < 4; nt++)
                    acc[mt][nt] = __builtin_amdgcn_mfma_f32_16x16x32_bf16(bf[nt], af[mt], acc[mt][nt], 0, 0, 0);
        }
    }
#pragma unroll
    for (int mt = 0; mt < 2; mt++) {
        int row = m0 + warp * 32 + mt * 16 + ln;
#pragma unroll
        for (int nt = 0; nt < 4; nt++) {
            int colb = n0 + nt * 16 + quad * 4;
            *(f32x4*)(Cout + (size_t)row * N + colb) = acc[mt][nt];
        }
    }
}

// ---------------- fused norm_rope (blocks < 12288) + v_transpose (rest) ----------------
// Vectorized: each 32-lane half-warp owns one (token, head) row; lane holds 4 dims
// d = 4*l5+{0..3} -> 8B loads/stores (was 2B scalar). RMSNorm reduce: 5 shfl_xor (<32,
// stays within half). RoPE partner d<->d+64 is exactly lane l5^16 (4*(l5^16) = 4*l5 +- 64).
// Q pre-scaled by (1/sqrt(128))*log2(e) so attn's QK^T lands in the exp2 domain.
__global__ __launch_bounds__(256) void nrvt(const unsigned short* __restrict__ QKV,
                                            const float* __restrict__ qw,
                                            const float* __restrict__ kw,
                                            unsigned short* __restrict__ Q,
                                            unsigned short* __restrict__ Kb,
                                            unsigned short* __restrict__ Vt) {
    if (blockIdx.x < 12288) {
        const int tid = threadIdx.x;
        const int l5 = tid & 31;
        const int task = blockIdx.x * 8 + (tid >> 5);   // 98304 tasks
        const int tok = task / 24;
        const int slot = task - tok * 24;
        const int b = tok >> 11, t = tok & 2047;
        const float* w;
        unsigned short* dst;
        int col0;
        float sc;
        if (slot < 16) {
            col0 = slot * HD;
            dst = Q + ((size_t)(b * 16 + slot) * TSEQ + t) * HD;
            w = qw;
            sc = 0.12750580997495268f;  // (1/sqrt(128)) * log2(e) folded into Q
        } else {
            int hk = slot - 16;
            col0 = QOUT + hk * HD;
            dst = Kb + ((size_t)(b * 8 + hk) * TSEQ + t) * HD;
            w = kw;
            sc = 1.0f;
        }
        const unsigned short* row = QKV + (size_t)tok * 4096 + col0;
        unsigned long long pkin = *(const unsigned long long*)(row + l5 * 4);
        unsigned short us[4];
        *(unsigned long long*)us = pkin;
        float e[4];
        float ss = 0.f;
#pragma unroll
        for (int k = 0; k < 4; k++) { e[k] = bf2f(us[k]); ss += e[k] * e[k]; }
#pragma unroll
        for (int off = 1; off < 32; off <<= 1) ss += __shfl_xor(ss, off);
        float rr = rsqrtf(ss * (1.0f / 128.0f) + 1e-6f);
        float4 wv = *(const float4*)(w + l5 * 4);
        float n[4] = { e[0] * rr * wv.x, e[1] * rr * wv.y, e[2] * rr * wv.z, e[3] * rr * wv.w };
        float np[4];
#pragma unroll
        for (int k = 0; k < 4; k++) np[k] = __shfl_xor(n[k], 16);
        const float tf = (float)t;
        const int fb = (l5 & 15) * 4;      // freq index base = d % 64
        const bool hi = (l5 >= 16);
        unsigned short outs[4];
#pragma unroll
        for (int k = 0; k < 4; k++) {
            float invf = __builtin_exp2f(-(float)(fb + k) * 0.20762050593045951f);
            float sf, cf;
            __sincosf(tf * invf, &sf, &cf);
            float o = hi ? (n[k] * cf + np[k] * sf) : (n[k] * cf - np[k] * sf);
            outs[k] = f2bf(o * sc);
        }
        *(unsigned long long*)(dst + l5 * 4) = *(unsigned long long*)outs;
        return;
    }
    // v_transpose
    __shared__ __attribute__((aligned(16))) unsigned short Ls[128 * 72];
    int bid = blockIdx.x - 12288;
    int tt = bid & 31, hk = (bid >> 5) & 7, b = bid >> 8;
    int t0 = tt * 64;
    int tid = threadIdx.x;
    const unsigned short* base = QKV + (size_t)(b * 2048 + t0) * 4096 + 3072 + hk * 128;
    for (int i = 0; i < 4; i++) {
        int idx = tid + i * 256;
        int r = idx >> 4, seg = idx & 15;
        uint4v v = *(const uint4v*)(base + (size_t)r * 4096 + seg * 8);
        unsigned short* pv = (unsigned short*)&v;
        int d = seg * 8;
        for (int jj = 0; jj < 8; jj++) Ls[(d + jj) * 72 + r] = pv[jj];
    }
    __syncthreads();
    unsigned short* out = Vt + (size_t)(b * 8 + hk) * 128 * 2048;
    for (int i = 0; i < 4; i++) {
        int idx = tid + i * 256;
        int d = idx >> 3, seg = idx & 7;
        uint4v v = *(const uint4v*)(Ls + d * 72 + seg * 8);
        *(uint4v*)(out + (size_t)d * 2048 + t0 + seg * 8) = v;
    }
}

// ---------------- flash attention v8 (round-1 best: 75.3us): defer-max + mfma row-sum ------
// grid (16 p, 32 b*h), 256 thr. Wave owns 16 rows of tile p (strip 0, active j<=p)
// and 16 rows of tile 31-p (strip 1, always active). Prefetch j+1 after the barrier.
// Softmax: lane-local max check (T13 THR=8, shuffle-free common path), row-sum l via
// 2 extra MFMAs against a ones-fragment, P packed with v_cvt_pk_bf16_f32.
__global__ __launch_bounds__(256, 2) void attn(const unsigned short* __restrict__ Q,
                                               const unsigned short* __restrict__ Kg,
                                               const unsigned short* __restrict__ Vt,
                                               unsigned short* __restrict__ Og) {
    __shared__ __attribute__((aligned(16))) unsigned short Ks[2][64 * 128];  // swizzled (kv, d)
    __shared__ __attribute__((aligned(16))) unsigned short Vs[2][128 * 64];  // swizzled (d, kv)
    __shared__ __attribute__((aligned(16))) unsigned short Ps[4][16 * 72];
    const int p = blockIdx.x;
    const int bh = blockIdx.y;
    const int b = bh >> 4, h = bh & 15, hk = h >> 1;
    const int tid = threadIdx.x;
    const int warp = tid >> 6, lane = tid & 63, ln = lane & 15, quad = lane >> 4;
    const int strip[2] = { p * 64 + warp * 16, (31 - p) * 64 + warp * 16 };
    const int jdiag[2] = { p, 31 - p };

    const unsigned short* Kbase = Kg + (size_t)(b * 8 + hk) * TSEQ * HD;
    const unsigned short* Vbase = Vt + (size_t)(b * 8 + hk) * HD * TSEQ;
    const unsigned short* Qh = Q + (size_t)(b * 16 + h) * TSEQ * HD;

    short8 qf[2][4];
#pragma unroll
    for (int st = 0; st < 2; st++)
#pragma unroll
        for (int kt = 0; kt < 4; kt++)
            qf[st][kt] = *(const short8*)(Qh + (size_t)(strip[st] + ln) * HD + kt * 32 + quad * 8);

    f32x4 o[2][8];
    f32x4 lac[2];
#pragma unroll
    for (int st = 0; st < 2; st++) {
        lac[st] = (f32x4){0.f, 0.f, 0.f, 0.f};
#pragma unroll
        for (int ot = 0; ot < 8; ot++) o[st][ot] = (f32x4){0.f, 0.f, 0.f, 0.f};
    }
    float m_[2] = {-1e30f, -1e30f};

    const int kr = lane >> 4;
    const int kc = lane & 15;
    const int vr = lane >> 3;
    const int vc = lane & 7;

    auto stage_kv = [&](int jt, int bi) {
        const int j0s = jt * 64;
        unsigned short* KsB = Ks[bi];
        unsigned short* VsB = Vs[bi];
#pragma unroll
        for (int c = 0; c < 4; c++) {   // K: LDS[r][c] = K[r][c ^ (r&15)]
            int row = warp * 16 + c * 4 + kr;
            glds16(Kbase + (size_t)(j0s + row) * HD + ((kc ^ (row & 15)) * 8),
                   KsB + (warp * 16 + c * 4) * 128);
        }
#pragma unroll
        for (int c = 0; c < 4; c++) {   // V^T: LDS[d][c] = V[d][c ^ (d&7)]
            int d = warp * 32 + c * 8 + vr;
            glds16(Vbase + (size_t)d * TSEQ + j0s + ((vc ^ (d & 7)) * 8),
                   VsB + (warp * 32 + c * 8) * 64);
        }
    };

    // bf16 1.0 fragment for row-sum MFMA (B = all-ones 16x32)
    short8 ones8;
#pragma unroll
    for (int i = 0; i < 8; i++) ones8[i] = (short)0x3F80;

    const int nT = 32 - p;
    stage_kv(0, 0);
    for (int j = 0; j < nT; j++) {
        __syncthreads();                 // drains my glds for buf j&1 (prev iter's prefetch)
        if (j + 1 < nT) stage_kv(j + 1, (j + 1) & 1);
        const unsigned short* KsC = Ks[j & 1];
        const unsigned short* VsC = Vs[j & 1];
        const bool act0 = (j <= jdiag[0]);
        // ---- QK^T for both strips, kf shared (Q pre-scaled: s is in exp2 domain) ----
        f32x4 s[2][4];
#pragma unroll
        for (int kb = 0; kb < 4; kb++) {
            s[0][kb] = (f32x4){0.f, 0.f, 0.f, 0.f};
            s[1][kb] = (f32x4){0.f, 0.f, 0.f, 0.f};
        }
        __builtin_amdgcn_s_setprio(1);
#pragma unroll
        for (int kt = 0; kt < 4; kt++) {
            short8 kf[4];
#pragma unroll
            for (int kb = 0; kb < 4; kb++)
                kf[kb] = *(const short8*)(KsC + (kb * 16 + ln) * 128 + (((kt * 4 + quad) ^ ln) * 8));
#pragma unroll
            for (int kb = 0; kb < 4; kb++)
                s[1][kb] = __builtin_amdgcn_mfma_f32_16x16x32_bf16(kf[kb], qf[1][kt], s[1][kb], 0, 0, 0);
            if (act0)
#pragma unroll
                for (int kb = 0; kb < 4; kb++)
                    s[0][kb] = __builtin_amdgcn_mfma_f32_16x16x32_bf16(kf[kb], qf[0][kt], s[0][kb], 0, 0, 0);
        }
        __builtin_amdgcn_s_setprio(0);
        // ---- softmax + P staging per strip: defer-max (THR=8), shuffle-free common path ----
        short8 pf[2][2];
        bool needR[2] = {false, false};
        float alpha[2] = {1.f, 1.f};
#pragma unroll
        for (int st = 0; st < 2; st++) {
            if (st == 0 && !act0) continue;
            float mk[4];
            if (j == jdiag[st]) {
                const int qloc = warp * 16 + ln;
#pragma unroll
                for (int kb = 0; kb < 4; kb++) {
#pragma unroll
                    for (int r = 0; r < 4; r++) {
                        int kvloc = kb * 16 + quad * 4 + r;
                        if (kvloc > qloc) s[st][kb][r] = -1e30f;
                    }
                    mk[kb] = fmaxf(fmaxf(s[st][kb][0], s[st][kb][1]),
                                   fmaxf(s[st][kb][2], s[st][kb][3]));
                }
            } else {
#pragma unroll
                for (int kb = 0; kb < 4; kb++)
                    mk[kb] = fmaxf(fmaxf(s[st][kb][0], s[st][kb][1]),
                                   fmaxf(s[st][kb][2], s[st][kb][3]));
            }
            float mx = fmaxf(fmaxf(mk[0], mk[1]), fmaxf(mk[2], mk[3]));
            float mn = m_[st];
            // lane-local max is a lower bound on the row max; if every lane is within
            // THR=8 of m, the row max is too -> keep m (P bounded by 2^8, bf16-safe).
            if (!__all(mx <= mn + 8.0f)) {
                mx = fmaxf(mx, __shfl_xor(mx, 16));
                mx = fmaxf(mx, __shfl_xor(mx, 32));
                mn = fmaxf(m_[st], mx);
                alpha[st] = __builtin_exp2f(m_[st] - mn);
                m_[st] = mn;
                needR[st] = true;
            }
#pragma unroll
            for (int kb = 0; kb < 4; kb++) {
                float p0 = __builtin_exp2f(s[st][kb][0] - mn);
                float p1 = __builtin_exp2f(s[st][kb][1] - mn);
                float p2 = __builtin_exp2f(s[st][kb][2] - mn);
                float p3 = __builtin_exp2f(s[st][kb][3] - mn);
                unsigned long long pk =
                    (unsigned long long)cvtpk(p0, p1) |
                    ((unsigned long long)cvtpk(p2, p3) << 32);
                *(unsigned long long*)(&Ps[warp][ln * 72 + kb * 16 + quad * 4]) = pk;
            }
            pf[st][0] = *(const short8*)(&Ps[warp][ln * 72 + quad * 8]);
            pf[st][1] = *(const short8*)(&Ps[warp][ln * 72 + 32 + quad * 8]);
        }
        // ---- rescale O and l (uniform branch, rare after first tile) ----
        if (act0 && needR[0]) {
            float a = alpha[0];
#pragma unroll
            for (int ot = 0; ot < 8; ot++)
#pragma unroll
                for (int r = 0; r < 4; r++) o[0][ot][r] *= a;
#pragma unroll
            for (int r = 0; r < 4; r++) lac[0][r] *= a;
        }
        if (needR[1]) {
            float a = alpha[1];
#pragma unroll
            for (int ot = 0; ot < 8; ot++)
#pragma unroll
                for (int r = 0; r < 4; r++) o[1][ot][r] *= a;
#pragma unroll
            for (int r = 0; r < 4; r++) lac[1][r] *= a;
        }
        // ---- PV + row-sum, vf shared across strips; operand-swapped (O: col=q=ln, rows=d) ----
        __builtin_amdgcn_s_setprio(1);
        lac[1] = __builtin_amdgcn_mfma_f32_16x16x32_bf16(ones8, pf[1][0], lac[1], 0, 0, 0);
        lac[1] = __builtin_amdgcn_mfma_f32_16x16x32_bf16(ones8, pf[1][1], lac[1], 0, 0, 0);
        if (act0) {
            lac[0] = __builtin_amdgcn_mfma_f32_16x16x32_bf16(ones8, pf[0][0], lac[0], 0, 0, 0);
            lac[0] = __builtin_amdgcn_mfma_f32_16x16x32_bf16(ones8, pf[0][1], lac[0], 0, 0, 0);
        }
#pragma unroll
        for (int ot = 0; ot < 8; ot++) {
            short8 vf0 = *(const short8*)(VsC + (ot * 16 + ln) * 64 + ((quad ^ (ln & 7)) * 8));
            short8 vf1 = *(const short8*)(VsC + (ot * 16 + ln) * 64 + (((4 + quad) ^ (ln & 7)) * 8));
            o[1][ot] = __builtin_amdgcn_mfma_f32_16x16x32_bf16(vf0, pf[1][0], o[1][ot], 0, 0, 0);
            o[1][ot] = __builtin_amdgcn_mfma_f32_16x16x32_bf16(vf1, pf[1][1], o[1][ot], 0, 0, 0);
            if (act0) {
                o[0][ot] = __builtin_amdgcn_mfma_f32_16x16x32_bf16(vf0, pf[0][0], o[0][ot], 0, 0, 0);
                o[0][ot] = __builtin_amdgcn_mfma_f32_16x16x32_bf16(vf1, pf[0][1], o[0][ot], 0, 0, 0);
            }
        }
        __builtin_amdgcn_s_setprio(0);
    }
    // epilogue: lane has q = strip+ln; regs are 4 consecutive d -> 8B stores
#pragma unroll
    for (int st = 0; st < 2; st++) {
        float inv = 1.0f / lac[st][0];
        size_t rowoff = ((size_t)(b * TSEQ + strip[st] + ln)) * QOUT + h * 128 + quad * 4;
#pragma unroll
        for (int ot = 0; ot < 8; ot++) {
            unsigned long long pk =
                (unsigned long long)cvtpk(o[st][ot][0] * inv, o[st][ot][1] * inv) |
                ((unsigned long long)cvtpk(o[st][ot][2] * inv, o[st][ot][3] * inv) << 32);
            *(unsigned long long*)(Og + rowoff + ot * 16) = pk;
        }
    }
}

extern "C" void kernel_launch(void* const* d_in, const int* in_sizes, int n_in,
                              void* d_out, int out_size, void* d_ws, size_t ws_size,
                              hipStream_t stream) {
    (void)in_sizes; (void)n_in; (void)out_size;
    const float* x  = (const float*)d_in[0];
    const float* Wq = (const float*)d_in[1];
    const float* Wk = (const float*)d_in[2];
    const float* Wv = (const float*)d_in[3];
    const float* Wo = (const float*)d_in[4];
    const float* qw = (const float*)d_in[5];
    const float* kw = (const float*)d_in[6];

    char* ws = (char*)d_ws;
    const size_t MB = 1024 * 1024;
    unsigned short* Wt   = (unsigned short*)(ws);            // 8 MB
    unsigned short* Wot  = (unsigned short*)(ws + 8 * MB);   // 4 MB
    unsigned short* QKVb = (unsigned short*)(ws + 12 * MB);  // 32 MB (bf16)
    unsigned short* xb   = (unsigned short*)(ws + 44 * MB);  // 8 MB
    unsigned short* Qb   = (unsigned short*)(ws + 52 * MB);  // 16 MB
    unsigned short* Kb   = (unsigned short*)(ws + 68 * MB);  // 8 MB
    unsigned short* Vtb  = (unsigned short*)(ws + 76 * MB);  // 8 MB
    unsigned short* Ob   = (unsigned short*)(ws + 84 * MB);  // 16 MB
    if (ws_size < 100 * MB) return;

    prep<<<dim3(5632), 256, 0, stream>>>(x, Wq, Wk, Wv, Wo, xb, Wt, Wot);
    gemm_bt<1, 128><<<dim3(32, 32), 256, 0, stream>>>(xb, Wt, QKVb, 4096, 4096, 1024);
    nrvt<<<dim3(12800), 256, 0, stream>>>(QKVb, qw, kw, Qb, Kb, Vtb);
    attn<<<dim3(16, 32), 256, 0, stream>>>(Qb, Kb, Vtb, Ob);
    gemm_o<<<dim3(16, 32), 256, 0, stream>>>(Ob, Wot, (float*)d_out, 4096, 1024, 2048);
}

// Round 4
// 249.214 us; speedup vs baseline: 1.1454x; 1.0477x over previous
//
#include <hip/hip_runtime.h>
#include <math.h>

typedef __attribute__((ext_vector_type(8))) short short8;
typedef __attribute__((ext_vector_type(4))) float f32x4;
typedef __attribute__((ext_vector_type(4))) unsigned int uint4v;

#define HIDDEN 1024
#define QOUT 2048
#define KVOUT 1024
#define HD 128
#define TSEQ 2048

__device__ __forceinline__ float bf2f(unsigned short h) {
    union { unsigned int u; float f; } x; x.u = ((unsigned int)h) << 16; return x.f;
}
__device__ __forceinline__ unsigned short f2bf(float f) {
    union { float f; unsigned int u; } x; x.f = f;
    unsigned int r = (x.u + 0x7fffu + ((x.u >> 16) & 1u)) >> 16;
    return (unsigned short)r;
}
// HW packed f32->bf16 (RNE, same semantics as f2bf pair) -- 1 VALU op per 2 values
__device__ __forceinline__ unsigned int cvtpk(float lo, float hi) {
    unsigned int r;
    asm("v_cvt_pk_bf16_f32 %0, %1, %2" : "=v"(r) : "v"(lo), "v"(hi));
    return r;
}

// async global->LDS, 16B per lane; dest = wave-uniform base + lane*16
__device__ __forceinline__ void glds16(const unsigned short* g, unsigned short* l) {
    __builtin_amdgcn_global_load_lds(
        (const __attribute__((address_space(1))) unsigned int*)g,
        (__attribute__((address_space(3))) unsigned int*)l, 16, 0, 0);
}

// ---------------- prep: cast x->bf16  +  4 weight transposes (fp32 KxN -> bf16 NxK) ---------
__global__ __launch_bounds__(256) void prep(const float* __restrict__ x,
                                            const float* __restrict__ Wq,
                                            const float* __restrict__ Wk,
                                            const float* __restrict__ Wv,
                                            const float* __restrict__ Wo,
                                            unsigned short* __restrict__ xb,
                                            unsigned short* __restrict__ Wt,
                                            unsigned short* __restrict__ Wot) {
    int bid = blockIdx.x;
    int tid = threadIdx.x;
    if (bid < 4096) {  // cast: 1M float4
        int i = bid * 256 + tid;
        float4 v = *(const float4*)(x + (size_t)i * 4);
        unsigned short o[4] = {f2bf(v.x), f2bf(v.y), f2bf(v.z), f2bf(v.w)};
        *(unsigned long long*)(xb + (size_t)i * 4) = *(unsigned long long*)o;
        return;
    }
    bid -= 4096;
    const float* W; unsigned short* D; int K, N;
    if (bid < 512)       { W = Wq; D = Wt;                          K = 1024; N = 2048; }
    else if (bid < 768)  { bid -= 512;  W = Wk; D = Wt + (size_t)2048 * 1024; K = 1024; N = 1024; }
    else if (bid < 1024) { bid -= 768;  W = Wv; D = Wt + (size_t)3072 * 1024; K = 1024; N = 1024; }
    else                 { bid -= 1024; W = Wo; D = Wot;                      K = 2048; N = 1024; }
    __shared__ __attribute__((aligned(16))) unsigned short Ls[64 * 72];
    int ntiles = N >> 6;
    int kt = bid / ntiles, nt = bid - kt * ntiles;
    int k0 = kt * 64, n0 = nt * 64;
    for (int t = 0; t < 4; t++) {
        int idx = tid + t * 256;
        int r = idx >> 4, seg = idx & 15;
        float4 v = *(const float4*)(W + (size_t)(k0 + r) * N + n0 + seg * 4);
        int c = seg * 4;
        Ls[(c + 0) * 72 + r] = f2bf(v.x);
        Ls[(c + 1) * 72 + r] = f2bf(v.y);
        Ls[(c + 2) * 72 + r] = f2bf(v.z);
        Ls[(c + 3) * 72 + r] = f2bf(v.w);
    }
    __syncthreads();
    for (int t = 0; t < 2; t++) {
        int idx = tid + t * 256;
        int rr = idx >> 3, seg = idx & 7;
        uint4v v = *(const uint4v*)(Ls + rr * 72 + seg * 8);
        *(uint4v*)(D + (size_t)(n0 + rr) * K + k0 + seg * 8) = v;
    }
}

// ---------------- GEMM (QKV): C[M,N] = A[M,K](bf16) @ Bt[N,K]^T(bf16), BK=32 ----------------
template <int OUT_BF16, int BN>
__global__ __launch_bounds__(256) void gemm_bt(const unsigned short* __restrict__ A,
                                               const unsigned short* __restrict__ Bt,
                                               void* __restrict__ Cout,
                                               int M, int N, int K) {
    constexpr int MT = (BN == 128) ? 4 : 2;
    __shared__ __attribute__((aligned(16))) unsigned short As[2][128 * 32];
    __shared__ __attribute__((aligned(16))) unsigned short Bs[2][BN * 32];
    const int tid = threadIdx.x;
    const int lane = tid & 63;
    const int warp = tid >> 6;
    const int ln = lane & 15;
    const int quad = lane >> 4;
    const int wm = (BN == 128) ? (warp >> 1) : warp;
    const int wn = (BN == 128) ? (warp & 1) : 0;
    const int m0 = blockIdx.y * 128;
    const int n0 = blockIdx.x * BN;

    const int srow = lane >> 2;
    const int schunk = (lane & 3) ^ (srow & 3);
    const unsigned short* Ag = A + (size_t)(m0 + warp * 16 + srow) * K + schunk * 8;
    const unsigned short* Bg = Bt + (size_t)(n0 + warp * 16 + srow) * K + schunk * 8;

    f32x4 acc[MT][4];
#pragma unroll
    for (int i = 0; i < MT; i++)
#pragma unroll
        for (int j = 0; j < 4; j++) acc[i][j] = (f32x4){0.f, 0.f, 0.f, 0.f};

    auto stage = [&](int k0, int bi) {
        glds16(Ag + k0, As[bi] + warp * 16 * 32);
        glds16(Ag + (size_t)64 * K + k0, As[bi] + warp * 16 * 32 + 64 * 32);
        glds16(Bg + k0, Bs[bi] + warp * 16 * 32);
        if (BN == 128) glds16(Bg + (size_t)64 * K + k0, Bs[bi] + warp * 16 * 32 + 64 * 32);
    };

    const int rq = quad ^ (ln & 3);   // swizzled read chunk
    const int KI = K >> 5;
    stage(0, 0);
    for (int it = 0; it < KI; it++) {
        __syncthreads();            // drains my glds for buf it&1
        if (it + 1 < KI) stage((it + 1) << 5, (it + 1) & 1);
        const unsigned short* Ab = As[it & 1];
        const unsigned short* Bb = Bs[it & 1];
        short8 af[MT], bf[4];
#pragma unroll
        for (int mt = 0; mt < MT; mt++)
            af[mt] = *(const short8*)(Ab + (wm * (MT * 16) + mt * 16 + ln) * 32 + rq * 8);
#pragma unroll
        for (int nt = 0; nt < 4; nt++)
            bf[nt] = *(const short8*)(Bb + (wn * 64 + nt * 16 + ln) * 32 + rq * 8);
#pragma unroll
        for (int mt = 0; mt < MT; mt++)
#pragma unroll
            for (int nt = 0; nt < 4; nt++)
                acc[mt][nt] = __builtin_amdgcn_mfma_f32_16x16x32_bf16(bf[nt], af[mt], acc[mt][nt], 0, 0, 0);
    }
#pragma unroll
    for (int mt = 0; mt < MT; mt++) {
        int row = m0 + wm * (MT * 16) + mt * 16 + ln;
#pragma unroll
        for (int nt = 0; nt < 4; nt++) {
            int colb = n0 + wn * 64 + nt * 16 + quad * 4;
            if (OUT_BF16) {
                unsigned long long pk =
                    (unsigned long long)cvtpk(acc[mt][nt][0], acc[mt][nt][1]) |
                    ((unsigned long long)cvtpk(acc[mt][nt][2], acc[mt][nt][3]) << 32);
                *(unsigned long long*)((unsigned short*)Cout + (size_t)row * N + colb) = pk;
            } else {
                *(f32x4*)((float*)Cout + (size_t)row * N + colb) = acc[mt][nt];
            }
        }
    }
}

// ---------------- GEMM (O-proj): BM=128, BN=64, BK=64 -- half the barriers of BK=32 ----------
// Same staging idiom extended to 8 chunks/row: LDS[row][pos] holds logical chunk pos^(row&7);
// glds dest is linear (lane -> row=l>>3, pos=l&7), so global src chunk = (l&7)^(l>>3).
// Read: rc = (ks*4+quad)^(ln&7) retrieves logical chunk ks*4+quad at row frag*16+ln.
__global__ __launch_bounds__(256) void gemm_o(const unsigned short* __restrict__ A,
                                              const unsigned short* __restrict__ Bt,
                                              float* __restrict__ Cout,
                                              int M, int N, int K) {
    __shared__ __attribute__((aligned(16))) unsigned short As[2][128 * 64];  // 32 KB
    __shared__ __attribute__((aligned(16))) unsigned short Bs[2][64 * 64];   // 16 KB
    const int tid = threadIdx.x;
    const int lane = tid & 63;
    const int warp = tid >> 6;
    const int ln = lane & 15;
    const int quad = lane >> 4;
    const int m0 = blockIdx.y * 128;
    const int n0 = blockIdx.x * 64;

    const int srow = lane >> 3;            // 0..7
    const int schunk = (lane & 7) ^ srow;  // inverse-swizzled source chunk
    const unsigned short* Ag = A + (size_t)(m0 + warp * 32 + srow) * K + schunk * 8;
    const unsigned short* Bg = Bt + (size_t)(n0 + warp * 16 + srow) * K + schunk * 8;

    f32x4 acc[2][4];
#pragma unroll
    for (int i = 0; i < 2; i++)
#pragma unroll
        for (int j = 0; j < 4; j++) acc[i][j] = (f32x4){0.f, 0.f, 0.f, 0.f};

    auto stage = [&](int k0, int bi) {
#pragma unroll
        for (int g = 0; g < 4; g++)   // A rows warp*32 + g*8 + srow
            glds16(Ag + (size_t)(g * 8) * K + k0, As[bi] + (warp * 32 + g * 8) * 64);
#pragma unroll
        for (int g = 0; g < 2; g++)   // B rows warp*16 + g*8 + srow
            glds16(Bg + (size_t)(g * 8) * K + k0, Bs[bi] + (warp * 16 + g * 8) * 64);
    };

    const int KI = K >> 6;
    stage(0, 0);
    for (int it = 0; it < KI; it++) {
        __syncthreads();            // drains my glds for buf it&1
        if (it + 1 < KI) stage((it + 1) << 6, (it + 1) & 1);
        const unsigned short* Ab = As[it & 1];
        const unsigned short* Bb = Bs[it & 1];
#pragma unroll
        for (int ks = 0; ks < 2; ks++) {
            const int rc = ((ks << 2) + quad) ^ (ln & 7);
            short8 af[2], bf[4];
#pragma unroll
            for (int mt = 0; mt < 2; mt++)
                af[mt] = *(const short8*)(Ab + (warp * 32 + mt * 16 + ln) * 64 + rc * 8);
#pragma unroll
            for (int nt = 0; nt < 4; nt++)
                bf[nt] = *(const short8*)(Bb + (nt * 16 + ln) * 64 + rc * 8);
#pragma unroll
            for (int mt = 0; mt < 2; mt++)
#pragma unroll
                for (int nt = 0; nt < 4; nt++)
                    acc[mt][nt] = __builtin_amdgcn_mfma_f32_16x16x32_bf16(bf[nt], af[mt], acc[mt][nt], 0, 0, 0);
        }
    }
#pragma unroll
    for (int mt = 0; mt < 2; mt++) {
        int row = m0 + warp * 32 + mt * 16 + ln;
#pragma unroll
        for (int nt = 0; nt < 4; nt++) {
            int colb = n0 + nt * 16 + quad * 4;
            *(f32x4*)(Cout + (size_t)row * N + colb) = acc[mt][nt];
        }
    }
}

// ---------------- fused norm_rope (blocks < 12288) + v_transpose (rest) ----------------
// Vectorized: each 32-lane half-warp owns one (token, head) row; lane holds 4 dims
// d = 4*l5+{0..3} -> 8B loads/stores. RMSNorm reduce: 5 shfl_xor. RoPE partner d<->d+64
// is lane l5^16. Q pre-scaled by (1/sqrt(128))*log2(e).
__global__ __launch_bounds__(256) void nrvt(const unsigned short* __restrict__ QKV,
                                            const float* __restrict__ qw,
                                            const float* __restrict__ kw,
                                            unsigned short* __restrict__ Q,
                                            unsigned short* __restrict__ Kb,
                                            unsigned short* __restrict__ Vt) {
    if (blockIdx.x < 12288) {
        const int tid = threadIdx.x;
        const int l5 = tid & 31;
        const int task = blockIdx.x * 8 + (tid >> 5);   // 98304 tasks
        const int tok = task / 24;
        const int slot = task - tok * 24;
        const int b = tok >> 11, t = tok & 2047;
        const float* w;
        unsigned short* dst;
        int col0;
        float sc;
        if (slot < 16) {
            col0 = slot * HD;
            dst = Q + ((size_t)(b * 16 + slot) * TSEQ + t) * HD;
            w = qw;
            sc = 0.12750580997495268f;  // (1/sqrt(128)) * log2(e) folded into Q
        } else {
            int hk = slot - 16;
            col0 = QOUT + hk * HD;
            dst = Kb + ((size_t)(b * 8 + hk) * TSEQ + t) * HD;
            w = kw;
            sc = 1.0f;
        }
        const unsigned short* row = QKV + (size_t)tok * 4096 + col0;
        unsigned long long pkin = *(const unsigned long long*)(row + l5 * 4);
        unsigned short us[4];
        *(unsigned long long*)us = pkin;
        float e[4];
        float ss = 0.f;
#pragma unroll
        for (int k = 0; k < 4; k++) { e[k] = bf2f(us[k]); ss += e[k] * e[k]; }
#pragma unroll
        for (int off = 1; off < 32; off <<= 1) ss += __shfl_xor(ss, off);
        float rr = rsqrtf(ss * (1.0f / 128.0f) + 1e-6f);
        float4 wv = *(const float4*)(w + l5 * 4);
        float n[4] = { e[0] * rr * wv.x, e[1] * rr * wv.y, e[2] * rr * wv.z, e[3] * rr * wv.w };
        float np[4];
#pragma unroll
        for (int k = 0; k < 4; k++) np[k] = __shfl_xor(n[k], 16);
        const float tf = (float)t;
        const int fb = (l5 & 15) * 4;      // freq index base = d % 64
        const bool hi = (l5 >= 16);
        unsigned short outs[4];
#pragma unroll
        for (int k = 0; k < 4; k++) {
            float invf = __builtin_exp2f(-(float)(fb + k) * 0.20762050593045951f);
            float sf, cf;
            __sincosf(tf * invf, &sf, &cf);
            float o = hi ? (n[k] * cf + np[k] * sf) : (n[k] * cf - np[k] * sf);
            outs[k] = f2bf(o * sc);
        }
        *(unsigned long long*)(dst + l5 * 4) = *(unsigned long long*)outs;
        return;
    }
    // v_transpose
    __shared__ __attribute__((aligned(16))) unsigned short Ls[128 * 72];
    int bid = blockIdx.x - 12288;
    int tt = bid & 31, hk = (bid >> 5) & 7, b = bid >> 8;
    int t0 = tt * 64;
    int tid = threadIdx.x;
    const unsigned short* base = QKV + (size_t)(b * 2048 + t0) * 4096 + 3072 + hk * 128;
    for (int i = 0; i < 4; i++) {
        int idx = tid + i * 256;
        int r = idx >> 4, seg = idx & 15;
        uint4v v = *(const uint4v*)(base + (size_t)r * 4096 + seg * 8);
        unsigned short* pv = (unsigned short*)&v;
        int d = seg * 8;
        for (int jj = 0; jj < 8; jj++) Ls[(d + jj) * 72 + r] = pv[jj];
    }
    __syncthreads();
    unsigned short* out = Vt + (size_t)(b * 8 + hk) * 128 * 2048;
    for (int i = 0; i < 4; i++) {
        int idx = tid + i * 256;
        int d = idx >> 3, seg = idx & 7;
        uint4v v = *(const uint4v*)(Ls + d * 72 + seg * 8);
        *(uint4v*)(out + (size_t)d * 2048 + t0 + seg * 8) = v;
    }
}

// ---------------- flash attention v10: 8 waves/block, 1 strip/wave, 16 waves/CU ------------
// grid (16 p, 32 b*h), 512 thr. Warps 0-3 own 16 rows each of tile p (active j<=p),
// warps 4-7 own tile 31-p (always active). Same tiles/balance as v8, but strip state per
// wave halves (o[8], ~96 VGPR) and LDS = K 32K + V 32K + chunk-major Ps 16K = 80KB exactly
// -> 2 blocks/CU = 16 waves/CU (was 8): doubles TLP to fill the ~57% per-wave idle cycles.
// Ps [warp][chunk8][row16][16B]: read addr = chunk*256+ln*16 -> bank ln*4&31, conflict-free
// with zero padding (the 72-pad layout would need 18KB and overflow the 80KB budget).
__global__ __launch_bounds__(512, 4) void attn(const unsigned short* __restrict__ Q,
                                               const unsigned short* __restrict__ Kg,
                                               const unsigned short* __restrict__ Vt,
                                               unsigned short* __restrict__ Og) {
    __shared__ __attribute__((aligned(16))) unsigned short Ks[2][64 * 128];  // swizzled (kv, d)
    __shared__ __attribute__((aligned(16))) unsigned short Vs[2][128 * 64];  // swizzled (d, kv)
    __shared__ __attribute__((aligned(16))) unsigned short Ps[8][8][16][8];  // [warp][chunk][row][16B]
    const int p = blockIdx.x;
    const int bh = blockIdx.y;
    const int b = bh >> 4, h = bh & 15, hk = h >> 1;
    const int tid = threadIdx.x;
    const int w = tid >> 6, lane = tid & 63, ln = lane & 15, quad = lane >> 4;
    const int sg = w >> 2;                    // strip group: 0 -> tile p, 1 -> tile 31-p
    const int wi = w & 3;
    const int tile = sg ? (31 - p) : p;
    const int jdiag = tile;                   // kv-tile index where the causal diagonal falls
    const int qrow0 = tile * 64 + wi * 16;    // this wave's 16 q-rows

    const unsigned short* Kbase = Kg + (size_t)(b * 8 + hk) * TSEQ * HD;
    const unsigned short* Vbase = Vt + (size_t)(b * 8 + hk) * HD * TSEQ;
    const unsigned short* Qh = Q + (size_t)(b * 16 + h) * TSEQ * HD;

    short8 qf[4];
#pragma unroll
    for (int kt = 0; kt < 4; kt++)
        qf[kt] = *(const short8*)(Qh + (size_t)(qrow0 + ln) * HD + kt * 32 + quad * 8);

    f32x4 o[8];
    f32x4 lac = (f32x4){0.f, 0.f, 0.f, 0.f};
#pragma unroll
    for (int ot = 0; ot < 8; ot++) o[ot] = (f32x4){0.f, 0.f, 0.f, 0.f};
    float m_ = -1e30f;

    const int kr = lane >> 4;
    const int kc = lane & 15;
    const int vr = lane >> 3;
    const int vc = lane & 7;

    // staging split across 8 warps: warp w stages K rows [w*8, w*8+8) and V d-rows
    // [w*16, w*16+16) -- 4 glds16 per warp per tile.
    auto stage_kv = [&](int jt, int bi) {
        const int j0s = jt * 64;
        unsigned short* KsB = Ks[bi];
        unsigned short* VsB = Vs[bi];
#pragma unroll
        for (int c = 0; c < 2; c++) {   // K: LDS[r][c] = K[r][c ^ (r&15)]
            int row = w * 8 + c * 4 + kr;
            glds16(Kbase + (size_t)(j0s + row) * HD + ((kc ^ (row & 15)) * 8),
                   KsB + (w * 8 + c * 4) * 128);
        }
#pragma unroll
        for (int c = 0; c < 2; c++) {   // V^T: LDS[d][c] = V[d][c ^ (d&7)]
            int d = w * 16 + c * 8 + vr;
            glds16(Vbase + (size_t)d * TSEQ + j0s + ((vc ^ (d & 7)) * 8),
                   VsB + (w * 16 + c * 8) * 64);
        }
    };

    // bf16 1.0 fragment for row-sum MFMA (B = all-ones 16x32)
    short8 ones8;
#pragma unroll
    for (int i = 0; i < 8; i++) ones8[i] = (short)0x3F80;

    unsigned short* Pw = &Ps[w][0][0][0];
    const int nT = 32 - p;
    stage_kv(0, 0);
    for (int j = 0; j < nT; j++) {
        __syncthreads();                 // drains my glds for buf j&1 (prev iter's prefetch)
        if (j + 1 < nT) stage_kv(j + 1, (j + 1) & 1);
        const unsigned short* KsC = Ks[j & 1];
        const unsigned short* VsC = Vs[j & 1];
        const bool act = sg ? true : (j <= jdiag);
        if (act) {
            // ---- QK^T (Q pre-scaled: s is in exp2 domain) ----
            f32x4 s[4];
#pragma unroll
            for (int kb = 0; kb < 4; kb++) s[kb] = (f32x4){0.f, 0.f, 0.f, 0.f};
            __builtin_amdgcn_s_setprio(1);
#pragma unroll
            for (int kt = 0; kt < 4; kt++) {
                short8 kf[4];
#pragma unroll
                for (int kb = 0; kb < 4; kb++)
                    kf[kb] = *(const short8*)(KsC + (kb * 16 + ln) * 128 + (((kt * 4 + quad) ^ ln) * 8));
#pragma unroll
                for (int kb = 0; kb < 4; kb++)
                    s[kb] = __builtin_amdgcn_mfma_f32_16x16x32_bf16(kf[kb], qf[kt], s[kb], 0, 0, 0);
            }
            __builtin_amdgcn_s_setprio(0);
            // ---- softmax: defer-max (THR=8), shuffle-free common path ----
            float mk[4];
            if (j == jdiag) {
                const int qloc = wi * 16 + ln;
#pragma unroll
                for (int kb = 0; kb < 4; kb++) {
#pragma unroll
                    for (int r = 0; r < 4; r++) {
                        int kvloc = kb * 16 + quad * 4 + r;
                        if (kvloc > qloc) s[kb][r] = -1e30f;
                    }
                    mk[kb] = fmaxf(fmaxf(s[kb][0], s[kb][1]), fmaxf(s[kb][2], s[kb][3]));
                }
            } else {
#pragma unroll
                for (int kb = 0; kb < 4; kb++)
                    mk[kb] = fmaxf(fmaxf(s[kb][0], s[kb][1]), fmaxf(s[kb][2], s[kb][3]));
            }
            float mx = fmaxf(fmaxf(mk[0], mk[1]), fmaxf(mk[2], mk[3]));
            float mn = m_;
            bool needR = false;
            float alpha = 1.f;
            if (!__all(mx <= mn + 8.0f)) {
                mx = fmaxf(mx, __shfl_xor(mx, 16));
                mx = fmaxf(mx, __shfl_xor(mx, 32));
                mn = fmaxf(m_, mx);
                alpha = __builtin_exp2f(m_ - mn);
                m_ = mn;
                needR = true;
            }
            // ---- P -> bf16, chunk-major Ps: chunk = 2*kb + (quad>>1), slot = quad&1 ----
#pragma unroll
            for (int kb = 0; kb < 4; kb++) {
                float p0 = __builtin_exp2f(s[kb][0] - mn);
                float p1 = __builtin_exp2f(s[kb][1] - mn);
                float p2 = __builtin_exp2f(s[kb][2] - mn);
                float p3 = __builtin_exp2f(s[kb][3] - mn);
                unsigned long long pk =
                    (unsigned long long)cvtpk(p0, p1) |
                    ((unsigned long long)cvtpk(p2, p3) << 32);
                *(unsigned long long*)(Pw + (2 * kb + (quad >> 1)) * 128 + ln * 8 + (quad & 1) * 4) = pk;
            }
            short8 pf0 = *(const short8*)(Pw + quad * 128 + ln * 8);
            short8 pf1 = *(const short8*)(Pw + (4 + quad) * 128 + ln * 8);
            // ---- rescale O and l (uniform branch, rare after first tile) ----
            if (needR) {
#pragma unroll
                for (int ot = 0; ot < 8; ot++)
#pragma unroll
                    for (int r = 0; r < 4; r++) o[ot][r] *= alpha;
#pragma unroll
                for (int r = 0; r < 4; r++) lac[r] *= alpha;
            }
            // ---- PV + row-sum; operand-swapped (O: col=q=ln, rows=d) ----
            __builtin_amdgcn_s_setprio(1);
            lac = __builtin_amdgcn_mfma_f32_16x16x32_bf16(ones8, pf0, lac, 0, 0, 0);
            lac = __builtin_amdgcn_mfma_f32_16x16x32_bf16(ones8, pf1, lac, 0, 0, 0);
#pragma unroll
            for (int ot = 0; ot < 8; ot++) {
                short8 vf0 = *(const short8*)(VsC + (ot * 16 + ln) * 64 + ((quad ^ (ln & 7)) * 8));
                short8 vf1 = *(const short8*)(VsC + (ot * 16 + ln) * 64 + (((4 + quad) ^ (ln & 7)) * 8));
                o[ot] = __builtin_amdgcn_mfma_f32_16x16x32_bf16(vf0, pf0, o[ot], 0, 0, 0);
                o[ot] = __builtin_amdgcn_mfma_f32_16x16x32_bf16(vf1, pf1, o[ot], 0, 0, 0);
            }
            __builtin_amdgcn_s_setprio(0);
        }
    }
    // epilogue: lane has q = qrow0+ln; regs are 4 consecutive d -> 8B stores
    float inv = 1.0f / lac[0];
    size_t rowoff = ((size_t)(b * TSEQ + qrow0 + ln)) * QOUT + h * 128 + quad * 4;
#pragma unroll
    for (int ot = 0; ot < 8; ot++) {
        unsigned long long pk =
            (unsigned long long)cvtpk(o[ot][0] * inv, o[ot][1] * inv) |
            ((unsigned long long)cvtpk(o[ot][2] * inv, o[ot][3] * inv) << 32);
        *(unsigned long long*)(Og + rowoff + ot * 16) = pk;
    }
}

extern "C" void kernel_launch(void* const* d_in, const int* in_sizes, int n_in,
                              void* d_out, int out_size, void* d_ws, size_t ws_size,
                              hipStream_t stream) {
    (void)in_sizes; (void)n_in; (void)out_size;
    const float* x  = (const float*)d_in[0];
    const float* Wq = (const float*)d_in[1];
    const float* Wk = (const float*)d_in[2];
    const float* Wv = (const float*)d_in[3];
    const float* Wo = (const float*)d_in[4];
    const float* qw = (const float*)d_in[5];
    const float* kw = (const float*)d_in[6];

    char* ws = (char*)d_ws;
    const size_t MB = 1024 * 1024;
    unsigned short* Wt   = (unsigned short*)(ws);            // 8 MB
    unsigned short* Wot  = (unsigned short*)(ws + 8 * MB);   // 4 MB
    unsigned short* QKVb = (unsigned short*)(ws + 12 * MB);  // 32 MB (bf16)
    unsigned short* xb   = (unsigned short*)(ws + 44 * MB);  // 8 MB
    unsigned short* Qb   = (unsigned short*)(ws + 52 * MB);  // 16 MB
    unsigned short* Kb   = (unsigned short*)(ws + 68 * MB);  // 8 MB
    unsigned short* Vtb  = (unsigned short*)(ws + 76 * MB);  // 8 MB
    unsigned short* Ob   = (unsigned short*)(ws + 84 * MB);  // 16 MB
    if (ws_size < 100 * MB) return;

    prep<<<dim3(5632), 256, 0, stream>>>(x, Wq, Wk, Wv, Wo, xb, Wt, Wot);
    gemm_bt<1, 128><<<dim3(32, 32), 256, 0, stream>>>(xb, Wt, QKVb, 4096, 4096, 1024);
    nrvt<<<dim3(12800), 256, 0, stream>>>(QKVb, qw, kw, Qb, Kb, Vtb);
    attn<<<dim3(16, 32), 512, 0, stream>>>(Qb, Kb, Vtb, Ob);
    gemm_o<<<dim3(16, 32), 256, 0, stream>>>(Ob, Wot, (float*)d_out, 4096, 1024, 2048);
}